// Round 11
// baseline (123.654 us; speedup 1.0000x reference)
//
#include <hip/hip_runtime.h>
#include <cstdint>
#include <cstddef>

// ---------------------------------------------------------------------------
// MHA forward: x[2,2048,1024] fp32, wqkv[3072,1024], wo[1024,1024], wo_b[1024]
// out = concat(y[2,2048,1024], k[2,16,2048,64], v[2,16,2048,64]) fp32
// Pipeline: cvt->bf16 (fused); QKV GEMM (256x256 deep-pipeline, counted vmcnt,
// Q pre-scaled); SPLIT-KV flash causal attn (no-max softmax => additive
// partials; qb>=16 split in 2, partials in dead xb/wqkvb ws) + combine;
// proj GEMM (128x128 m97-structure).
// ---------------------------------------------------------------------------

using bf16x8 = __attribute__((ext_vector_type(8))) __bf16;
using f32x4  = __attribute__((ext_vector_type(4))) float;
using u16    = unsigned short;

#define SOFT_SCALE 0.1803368801111244f   // 0.125 * log2(e)  (attn in exp2 domain)

// fp32 -> bf16 bits, round-to-nearest-even
__device__ __forceinline__ u16 f2bf(float f) {
  union { float f; uint32_t u; } a; a.f = f;
  uint32_t r = a.u + 0x7fffu + ((a.u >> 16) & 1u);
  return (u16)(r >> 16);
}

__device__ __forceinline__ float bf2f(u16 u) {
  union { uint32_t u; float f; } a; a.u = ((uint32_t)u) << 16;
  return a.f;
}

__device__ __forceinline__ bf16x8 ldfrag(const u16* p) {
  return *reinterpret_cast<const bf16x8*>(p);
}

__device__ __forceinline__ void gload_lds16(const void* g, void* l) {
  __builtin_amdgcn_global_load_lds((const __attribute__((address_space(1))) void*)g,
                                   (__attribute__((address_space(3))) void*)l,
                                   16, 0, 0);
}

// pack two fp32 -> one u32 of two bf16 (lo = a, hi = b), RNE
__device__ __forceinline__ uint32_t cvt_pk_bf16(float a, float b) {
  uint32_t r;
  asm("v_cvt_pk_bf16_f32 %0, %1, %2" : "=v"(r) : "v"(a), "v"(b));
  return r;
}

// ---------------------------------------------------------------------------
// fused fp32 -> bf16 convert for x, wqkv, wo (single launch)
// ---------------------------------------------------------------------------
__global__ void cvt_all(const float* __restrict__ x, const float* __restrict__ wqkv,
                        const float* __restrict__ wo,
                        u16* __restrict__ xb, u16* __restrict__ wqkvb, u16* __restrict__ wob) {
  int i = blockIdx.x * blockDim.x + threadIdx.x;
  int stride = gridDim.x * blockDim.x;
  for (; i < 2097152; i += stride) {
    const float* src; u16* dst; int j;
    if (i < 1048576)      { src = x;    dst = xb;    j = i; }
    else if (i < 1835008) { src = wqkv; dst = wqkvb; j = i - 1048576; }
    else                  { src = wo;   dst = wob;   j = i - 1835008; }
    float4 v = reinterpret_cast<const float4*>(src)[j];
    ushort4 o;
    o.x = f2bf(v.x); o.y = f2bf(v.y); o.z = f2bf(v.z); o.w = f2bf(v.w);
    reinterpret_cast<ushort4*>(dst)[j] = o;
  }
}

// ---------------------------------------------------------------------------
// QKV GEMM, deep-pipelined: X[4096][1024] x Wqkv[3072][1024]^T, tile 256x256.
// (validated round 6; Q output pre-scaled by SOFT_SCALE — validated round 9)
// ---------------------------------------------------------------------------
__global__ __launch_bounds__(512, 2) void qkv_gemm_kernel(
    const u16* __restrict__ Xb, const u16* __restrict__ Wb,
    u16* __restrict__ Qws, u16* __restrict__ Kws, u16* __restrict__ Vtws,
    float* __restrict__ out) {
  extern __shared__ char smem[];   // [2][32KB] A then [2][32KB] B

  const int tid = threadIdx.x, lane = tid & 63, wid = tid >> 6;
  const int wr = wid >> 2, wc = wid & 3;
  const int fq = lane >> 4, fr = lane & 15;

  const int wg = (blockIdx.x & 7) * 24 + (blockIdx.x >> 3);
  const int bm = wg / 12, bn = wg % 12;
  const int m0 = bm * 256, n0 = bn * 256;

  const char* Ab = (const char*)Xb + (size_t)m0 * 2048;
  const char* Bb = (const char*)Wb + (size_t)n0 * 2048;

  f32x4 acc[8][4] = {};

  auto stage = [&](int t, int cc) {
    char* As = smem + cc * 32768;
    char* Bs = smem + 65536 + cc * 32768;
#pragma unroll
    for (int f = 0; f < 4; ++f) {
      int lin = (f * 512 + tid) * 16;
      int row = lin >> 7;
      int col = (lin & 127) ^ ((row & 7) << 4);
      gload_lds16(Ab + (size_t)row * 2048 + t * 128 + col, As + lin);
      gload_lds16(Bb + (size_t)row * 2048 + t * 128 + col, Bs + lin);
    }
  };

  stage(0, 0);
  int cur = 0;
  for (int t = 0; t < 16; ++t) {
    if (t < 15) {
      stage(t + 1, cur ^ 1);
      asm volatile("s_waitcnt vmcnt(8)" ::: "memory");
    } else {
      asm volatile("s_waitcnt vmcnt(0)" ::: "memory");
    }
    __builtin_amdgcn_s_barrier();
    __builtin_amdgcn_sched_barrier(0);

    const char* As = smem + cur * 32768;
    const char* Bs = smem + 65536 + cur * 32768;

#pragma unroll
    for (int ks = 0; ks < 2; ++ks) {
      bf16x8 af[8];
#pragma unroll
      for (int m = 0; m < 8; ++m) {
        int row = wr * 128 + m * 16 + fr;
        int col = (ks * 64 + fq * 16) ^ ((row & 7) << 4);
        af[m] = *(const bf16x8*)(As + row * 128 + col);
      }
#pragma unroll
      for (int nh = 0; nh < 2; ++nh) {
        int row0 = wc * 64 + (nh * 2) * 16 + fr;
        int col0 = (ks * 64 + fq * 16) ^ ((row0 & 7) << 4);
        bf16x8 bf0 = *(const bf16x8*)(Bs + row0 * 128 + col0);
        int row1 = wc * 64 + (nh * 2 + 1) * 16 + fr;
        int col1 = (ks * 64 + fq * 16) ^ ((row1 & 7) << 4);
        bf16x8 bf1 = *(const bf16x8*)(Bs + row1 * 128 + col1);
        __builtin_amdgcn_s_setprio(1);
#pragma unroll
        for (int m = 0; m < 8; ++m) {
          acc[m][nh * 2]     = __builtin_amdgcn_mfma_f32_16x16x32_bf16(af[m], bf0, acc[m][nh * 2], 0, 0, 0);
          acc[m][nh * 2 + 1] = __builtin_amdgcn_mfma_f32_16x16x32_bf16(af[m], bf1, acc[m][nh * 2 + 1], 0, 0, 0);
        }
        __builtin_amdgcn_s_setprio(0);
      }
    }
    asm volatile("s_waitcnt lgkmcnt(0)" ::: "memory");
    __builtin_amdgcn_s_barrier();
    cur ^= 1;
  }

  const int sect = n0 >> 10;
  const int nn0 = (n0 & 1023) + wc * 64;
  const int mbase = m0 + wr * 128;
#pragma unroll
  for (int m = 0; m < 8; ++m)
#pragma unroll
    for (int n = 0; n < 4; ++n) {
      int mB = mbase + m * 16 + fq * 4;
      int ncol = nn0 + n * 16 + fr;
      int b = mB >> 11, s0 = mB & 2047;
      int h = ncol >> 6, hd = ncol & 63;
      size_t base = (((size_t)b * 16 + h) * 2048 + s0) * 64 + hd;
      float v0 = acc[m][n][0], v1 = acc[m][n][1], v2 = acc[m][n][2], v3 = acc[m][n][3];
      if (sect == 0) {
        Qws[base]       = f2bf(v0 * SOFT_SCALE);
        Qws[base + 64]  = f2bf(v1 * SOFT_SCALE);
        Qws[base + 128] = f2bf(v2 * SOFT_SCALE);
        Qws[base + 192] = f2bf(v3 * SOFT_SCALE);
      } else if (sect == 1) {
        Kws[base] = f2bf(v0); Kws[base + 64] = f2bf(v1);
        Kws[base + 128] = f2bf(v2); Kws[base + 192] = f2bf(v3);
        out[4194304 + base] = v0; out[4194304 + base + 64] = v1;
        out[4194304 + base + 128] = v2; out[4194304 + base + 192] = v3;
      } else {
        out[8388608 + base] = v0; out[8388608 + base + 64] = v1;
        out[8388608 + base + 128] = v2; out[8388608 + base + 192] = v3;
        size_t tt = ((size_t)(b * 16 + h) * 64 + hd) * 2048 + s0;
        ushort4 pk; pk.x = f2bf(v0); pk.y = f2bf(v1); pk.z = f2bf(v2); pk.w = f2bf(v3);
        *reinterpret_cast<ushort4*>(Vtws + tt) = pk;
      }
    }
}

// ---------------------------------------------------------------------------
// 128x128 tile GEMM core (m97 structure) — used by proj only.
// ---------------------------------------------------------------------------
__device__ __forceinline__ void gemm128_core(const u16* __restrict__ A,
                                             const u16* __restrict__ B,
                                             int m0, int n0, int K,
                                             u16* As, u16* Bs, f32x4 acc[4][4]) {
  const int tid  = threadIdx.x;
  const int lane = tid & 63;
  const int wid  = tid >> 6;
  const int wr = wid >> 1, wc = wid & 1;
  const int fq = lane >> 4, fr = lane & 15;

  for (int kb = 0; kb < K; kb += 32) {
#pragma unroll
    for (int j = 0; j < 2; ++j) {
      int lin = (j * 256 + tid) * 16;
      int row = lin >> 6;
      int rb  = lin & 63;
      gload_lds16((const char*)(A + (size_t)(m0 + row) * K + kb) + rb, (char*)As + lin);
      gload_lds16((const char*)(B + (size_t)(n0 + row) * K + kb) + rb, (char*)Bs + lin);
    }
    __syncthreads();

    bf16x8 av[4], bv[4];
#pragma unroll
    for (int i = 0; i < 4; ++i) av[i] = ldfrag(As + (wr * 64 + i * 16 + fr) * 32 + fq * 8);
#pragma unroll
    for (int j = 0; j < 4; ++j) bv[j] = ldfrag(Bs + (wc * 64 + j * 16 + fr) * 32 + fq * 8);
    __builtin_amdgcn_s_setprio(1);
#pragma unroll
    for (int i = 0; i < 4; ++i)
#pragma unroll
      for (int j = 0; j < 4; ++j)
        acc[i][j] = __builtin_amdgcn_mfma_f32_16x16x32_bf16(av[i], bv[j], acc[i][j], 0, 0, 0);
    __builtin_amdgcn_s_setprio(0);
    __syncthreads();
  }
}

// ---------------------------------------------------------------------------
// SPLIT-KV flash causal attention. grid = 48 jobs x 32 bh = 1536; block 256.
// Jobs (heavy first): j in [0,32): qb = 31-(j>>1), split s = j&1 (2 splits);
// j in [32,48): qb = 47-j, unsplit. Split job s handles KV tiles [s*len,
// min((s+1)*len, qb+1)), len = ceil((qb+1)/2). No-max softmax => partials are
// ADDITIVE: split jobs write unnormalized bf16 accO + fp32 row-sums to ws;
// combine kernel merges. Inner loop identical to r10 (proven).
// ---------------------------------------------------------------------------
__global__ __launch_bounds__(256, 4) void attn_kernel(
    const u16* __restrict__ Qw, const u16* __restrict__ Kw,
    const u16* __restrict__ Vtw, u16* __restrict__ Ow,
    u16* __restrict__ Pb, float* __restrict__ Sb) {
  __shared__ u16 Ks[2][64 * 64];
  __shared__ u16 Vs[2][64 * 64];

  const int tid = threadIdx.x, lane = tid & 63, wid = tid >> 6;
  const int fq = lane >> 4, fr = lane & 15;
  const int bh = blockIdx.x & 31;
  const int j  = blockIdx.x >> 5;          // 0..47, heavy first
  int qb, sp, nsplit;
  if (j < 32) { qb = 31 - (j >> 1); sp = j & 1; nsplit = 2; }
  else        { qb = 47 - j;        sp = 0;     nsplit = 1; }
  const int len = (qb + 2) >> 1;           // ceil((qb+1)/2)
  const int lo  = (nsplit == 2) ? sp * len : 0;
  const int hi  = (nsplit == 2) ? min(lo + len, qb + 1) : qb + 1;
  const int b = bh >> 4, h = bh & 15;
  const int q0 = qb * 64;

  const u16* Qbase  = Qw  + (size_t)bh * 2048 * 64;
  const u16* Kbase  = Kw  + (size_t)bh * 2048 * 64;
  const char* VtBase = (const char*)(Vtw + (size_t)bh * 64 * 2048);

  // stage KV tile kt into buffer cc (inverse-swizzled source)
  auto stageKV = [&](int kt, int cc) {
#pragma unroll
    for (int f = 0; f < 2; ++f) {
      int lin = (f * 256 + tid) * 16;
      int row = lin >> 7;
      int logical = lin ^ ((row & 7) << 4);
      gload_lds16((const char*)Kbase + (size_t)kt * 8192 + logical, (char*)Ks[cc] + lin);
      gload_lds16(VtBase + (size_t)row * 4096 + (size_t)kt * 128 + (logical & 127),
                  (char*)Vs[cc] + lin);
    }
  };

  stageKV(lo, 0);

  // ---- Q fragments: wave's 16 q-rows, q = fr (pre-scaled upstream)
  const int qrow = q0 + wid * 16 + fr;
  bf16x8 qa0 = ldfrag(Qbase + (size_t)qrow * 64 + fq * 8);
  bf16x8 qa1 = ldfrag(Qbase + (size_t)qrow * 64 + 32 + fq * 8);

  float ssum = 0.f;        // partial row sum for q = fr
  f32x4 accO[4] = {};

  int cur = 0;
  for (int kb = lo; kb < hi; ++kb) {
    __syncthreads();   // buf[cur] staged; all waves past prev reads

    if (kb + 1 < hi) stageKV(kb + 1, cur ^ 1);

    const u16* Kc = Ks[cur];
    const u16* Vc = Vs[cur];

    // ---- S^T = K Q^T (swapped): lane gets S[q=fr][kv=n*16+fq*4+r]
    f32x4 sfr[4];
    __builtin_amdgcn_s_setprio(1);
#pragma unroll
    for (int n = 0; n < 4; ++n) {
      int krow = n * 16 + fr;
      bf16x8 kf0 = ldfrag(Kc + krow * 64 + ((fq * 8)      ^ ((krow & 7) << 3)));
      bf16x8 kf1 = ldfrag(Kc + krow * 64 + ((fq * 8 + 32) ^ ((krow & 7) << 3)));
      f32x4 z = {};
      z = __builtin_amdgcn_mfma_f32_16x16x32_bf16(kf0, qa0, z, 0, 0, 0);
      z = __builtin_amdgcn_mfma_f32_16x16x32_bf16(kf1, qa1, z, 0, 0, 0);
      sfr[n] = z;
    }
    __builtin_amdgcn_s_setprio(0);

    // ---- p = exp2(s); mask on diagonal tile (only last split can hit it)
    uint32_t W[4][2];
#pragma unroll
    for (int n = 0; n < 4; ++n) {
      float p0, p1, p2, p3;
      if (kb < qb) {
        p0 = exp2f(sfr[n][0]);
        p1 = exp2f(sfr[n][1]);
        p2 = exp2f(sfr[n][2]);
        p3 = exp2f(sfr[n][3]);
      } else {
        int kvg = kb * 64 + n * 16 + fq * 4;
        p0 = (kvg + 0 > qrow) ? 0.f : exp2f(sfr[n][0]);
        p1 = (kvg + 1 > qrow) ? 0.f : exp2f(sfr[n][1]);
        p2 = (kvg + 2 > qrow) ? 0.f : exp2f(sfr[n][2]);
        p3 = (kvg + 3 > qrow) ? 0.f : exp2f(sfr[n][3]);
      }
      ssum += (p0 + p1) + (p2 + p3);
      W[n][0] = cvt_pk_bf16(p0, p1);
      W[n][1] = cvt_pk_bf16(p2, p3);
    }

    // ---- in-register P redistribution (swap32 then swap16)
    union { uint32_t u[4]; bf16x8 v; } pa0u, pa1u;
#pragma unroll
    for (int hh = 0; hh < 2; ++hh) {
      uint32_t a0 = W[0][hh], b0 = W[1][hh];
      asm("v_permlane32_swap_b32 %0, %1" : "+v"(a0), "+v"(b0));
      asm("v_permlane16_swap_b32 %0, %1" : "+v"(a0), "+v"(b0));
      pa0u.u[hh] = a0; pa0u.u[2 + hh] = b0;
      uint32_t a1 = W[2][hh], b1 = W[3][hh];
      asm("v_permlane32_swap_b32 %0, %1" : "+v"(a1), "+v"(b1));
      asm("v_permlane16_swap_b32 %0, %1" : "+v"(a1), "+v"(b1));
      pa1u.u[hh] = a1; pa1u.u[2 + hh] = b1;
    }

    // ---- O += P V : swizzled V^T reads; P from registers
    __builtin_amdgcn_s_setprio(1);
#pragma unroll
    for (int nh = 0; nh < 4; ++nh) {
      int vrow = nh * 16 + fr;
      bf16x8 vb0 = ldfrag(Vc + vrow * 64 + ((fq * 8)      ^ ((vrow & 7) << 3)));
      bf16x8 vb1 = ldfrag(Vc + vrow * 64 + ((fq * 8 + 32) ^ ((vrow & 7) << 3)));
      accO[nh] = __builtin_amdgcn_mfma_f32_16x16x32_bf16(pa0u.v, vb0, accO[nh], 0, 0, 0);
      accO[nh] = __builtin_amdgcn_mfma_f32_16x16x32_bf16(pa1u.v, vb1, accO[nh], 0, 0, 0);
    }
    __builtin_amdgcn_s_setprio(0);
    cur ^= 1;
  }

  // ---- total partial row-sum for q=fr (sum the 4 fq copies)
  ssum += __shfl_xor(ssum, 16);
  ssum += __shfl_xor(ssum, 32);

  if (nsplit == 1) {
    // direct normalized write
    float inv = 1.0f / ssum;
    float invq[4];
#pragma unroll
    for (int r = 0; r < 4; ++r) invq[r] = __shfl(inv, fq * 4 + r);
#pragma unroll
    for (int nh = 0; nh < 4; ++nh)
#pragma unroll
      for (int r = 0; r < 4; ++r) {
        float o = accO[nh][r] * invq[r];
        int qr = q0 + wid * 16 + fq * 4 + r;
        Ow[((size_t)b * 2048 + qr) * 1024 + h * 64 + nh * 16 + fr] = f2bf(o);
      }
  } else {
    // partial write: slot = ((bh*16 + qb-16)*2 + sp)
    int slot = ((bh * 16 + (qb - 16)) << 1) + sp;
    u16* po = Pb + (size_t)slot * 4096;          // [64 q][64 hd] bf16
    if (fq == 0) Sb[slot * 64 + wid * 16 + fr] = ssum;
#pragma unroll
    for (int nh = 0; nh < 4; ++nh)
#pragma unroll
      for (int r = 0; r < 4; ++r) {
        int ql = wid * 16 + fq * 4 + r;
        po[ql * 64 + nh * 16 + fr] = f2bf(accO[nh][r]);
      }
  }
}

// ---------------------------------------------------------------------------
// Combine split-KV partials: O = (P0 + P1) / (s0 + s1), write bf16 o_ws.
// grid = 32 bh x 16 qb(>=16) = 512; block 256 (thread: q = t>>2, 16 hd).
// ---------------------------------------------------------------------------
__global__ __launch_bounds__(256) void attn_combine(
    const u16* __restrict__ Pb, const float* __restrict__ Sb,
    u16* __restrict__ Ow) {
  int idx = blockIdx.x;
  int bh = idx >> 4, qq = idx & 15;
  int qb = 16 + qq;
  int slot = (bh * 16 + qq) << 1;
  const u16* p0 = Pb + (size_t)slot * 4096;
  const float* s0 = Sb + slot * 64;
  int t = threadIdx.x;
  int q = t >> 2, c0 = (t & 3) * 16;
  float inv = 1.0f / (s0[q] + s0[64 + q]);
  int b = bh >> 4, h = bh & 15;
  int qr = qb * 64 + q;
  size_t obase = ((size_t)b * 2048 + qr) * 1024 + h * 64 + c0;

  union { uint4 v[2]; u16 e[16]; } a, bb, o;
  a.v[0]  = *(const uint4*)(p0 + q * 64 + c0);
  a.v[1]  = *(const uint4*)(p0 + q * 64 + c0 + 8);
  bb.v[0] = *(const uint4*)(p0 + 4096 + q * 64 + c0);
  bb.v[1] = *(const uint4*)(p0 + 4096 + q * 64 + c0 + 8);
#pragma unroll
  for (int e = 0; e < 16; ++e) {
    float v = bf2f(a.e[e]) + bf2f(bb.e[e]);
    o.e[e] = f2bf(v * inv);
  }
  *(uint4*)(Ow + obase)     = o.v[0];
  *(uint4*)(Ow + obase + 8) = o.v[1];
}

// ---------------------------------------------------------------------------
// Output projection: O[4096][1024] x Wo[1024][1024]^T + b -> y fp32
// ---------------------------------------------------------------------------
__global__ __launch_bounds__(256) void proj_gemm_kernel(
    const u16* __restrict__ Ob, const u16* __restrict__ Wob,
    const float* __restrict__ bias, float* __restrict__ out) {
  __shared__ u16 As[128 * 32];
  __shared__ u16 Bs[128 * 32];
  const int NB = 8;
  int m0 = (blockIdx.x / NB) * 128, n0 = (blockIdx.x % NB) * 128;
  f32x4 acc[4][4] = {};
  gemm128_core(Ob, Wob, m0, n0, 1024, As, Bs, acc);

  const int lane = threadIdx.x & 63, wid = threadIdx.x >> 6;
  const int wr = wid >> 1, wc = wid & 1, fq = lane >> 4, fr = lane & 15;
#pragma unroll
  for (int i = 0; i < 4; ++i)
#pragma unroll
    for (int j = 0; j < 4; ++j)
#pragma unroll
      for (int r = 0; r < 4; ++r) {
        int m = m0 + wr * 64 + i * 16 + fq * 4 + r;
        int n = n0 + wc * 64 + j * 16 + fr;
        out[(size_t)m * 1024 + n] = acc[i][j][r] + bias[n];
      }
}

// ---------------------------------------------------------------------------
extern "C" void kernel_launch(void* const* d_in, const int* in_sizes, int n_in,
                              void* d_out, int out_size, void* d_ws, size_t ws_size,
                              hipStream_t stream) {
  const float* x    = (const float*)d_in[0];
  const float* wqkv = (const float*)d_in[1];
  const float* wo   = (const float*)d_in[2];
  const float* wo_b = (const float*)d_in[3];
  float* out = (float*)d_out;

  u16* xb    = (u16*)d_ws;            // 4096*1024  (reused as attn partial O)
  u16* wqkvb = xb    + 4194304;       // 3072*1024  (reused as attn partial S)
  u16* wob   = wqkvb + 3145728;       // 1024*1024
  u16* q_ws  = wob   + 1048576;       // [2,16,2048,64] (pre-scaled)
  u16* k_ws  = q_ws  + 4194304;       // [2,16,2048,64]
  u16* vt_ws = k_ws  + 4194304;       // [2,16,64,2048]  (V^T)
  u16* o_ws  = vt_ws + 4194304;       // [4096,1024]

  // attn partials live in the xb/wqkvb region (dead after qkv_gemm):
  u16*   part_o = xb;                 // 1024 slots x [64][64] bf16 = 4194304 u16
  float* part_s = (float*)wqkvb;      // 1024 slots x 64 fp32

  static bool attr_set = false;
  if (!attr_set) {
    hipFuncSetAttribute((const void*)qkv_gemm_kernel,
                        hipFuncAttributeMaxDynamicSharedMemorySize, 131072);
    attr_set = true;
  }

  cvt_all<<<2048, 256, 0, stream>>>(x, wqkv, wo, xb, wqkvb, wob);
  qkv_gemm_kernel<<<192, 512, 131072, stream>>>(xb, wqkvb, q_ws, k_ws, vt_ws, out);
  attn_kernel<<<48 * 32, 256, 0, stream>>>(q_ws, k_ws, vt_ws, o_ws, part_o, part_s);
  attn_combine<<<512, 256, 0, stream>>>(part_o, part_s, o_ws);
  proj_gemm_kernel<<<32 * 8, 256, 0, stream>>>(o_ws, wob, wo_b, out);
}

// Round 12
// 117.817 us; speedup vs baseline: 1.0495x; 1.0495x over previous
//
#include <hip/hip_runtime.h>
#include <cstdint>
#include <cstddef>

// ---------------------------------------------------------------------------
// MHA forward: x[2,2048,1024] fp32, wqkv[3072,1024], wo[1024,1024], wo_b[1024]
// out = concat(y[2,2048,1024], k[2,16,2048,64], v[2,16,2048,64]) fp32
// Pipeline: cvt->bf16 (fused); QKV GEMM (256x256, 4-phase fine interleave per
// K-tile, counted vmcnt(4), Q pre-scaled); flash causal attn (r10: swapped
// QK^T + permlane in-reg P, 32KB LDS); proj GEMM (128x128 m97-structure).
// ---------------------------------------------------------------------------

using bf16x8 = __attribute__((ext_vector_type(8))) __bf16;
using f32x4  = __attribute__((ext_vector_type(4))) float;
using u16    = unsigned short;

#define SOFT_SCALE 0.1803368801111244f   // 0.125 * log2(e)  (attn in exp2 domain)

// fp32 -> bf16 bits, round-to-nearest-even
__device__ __forceinline__ u16 f2bf(float f) {
  union { float f; uint32_t u; } a; a.f = f;
  uint32_t r = a.u + 0x7fffu + ((a.u >> 16) & 1u);
  return (u16)(r >> 16);
}

__device__ __forceinline__ bf16x8 ldfrag(const u16* p) {
  return *reinterpret_cast<const bf16x8*>(p);
}

__device__ __forceinline__ void gload_lds16(const void* g, void* l) {
  __builtin_amdgcn_global_load_lds((const __attribute__((address_space(1))) void*)g,
                                   (__attribute__((address_space(3))) void*)l,
                                   16, 0, 0);
}

// pack two fp32 -> one u32 of two bf16 (lo = a, hi = b), RNE
__device__ __forceinline__ uint32_t cvt_pk_bf16(float a, float b) {
  uint32_t r;
  asm("v_cvt_pk_bf16_f32 %0, %1, %2" : "=v"(r) : "v"(a), "v"(b));
  return r;
}

// ---------------------------------------------------------------------------
// fused fp32 -> bf16 convert for x, wqkv, wo (single launch)
// ---------------------------------------------------------------------------
__global__ void cvt_all(const float* __restrict__ x, const float* __restrict__ wqkv,
                        const float* __restrict__ wo,
                        u16* __restrict__ xb, u16* __restrict__ wqkvb, u16* __restrict__ wob) {
  int i = blockIdx.x * blockDim.x + threadIdx.x;
  int stride = gridDim.x * blockDim.x;
  for (; i < 2097152; i += stride) {
    const float* src; u16* dst; int j;
    if (i < 1048576)      { src = x;    dst = xb;    j = i; }
    else if (i < 1835008) { src = wqkv; dst = wqkvb; j = i - 1048576; }
    else                  { src = wo;   dst = wob;   j = i - 1835008; }
    float4 v = reinterpret_cast<const float4*>(src)[j];
    ushort4 o;
    o.x = f2bf(v.x); o.y = f2bf(v.y); o.z = f2bf(v.z); o.w = f2bf(v.w);
    reinterpret_cast<ushort4*>(dst)[j] = o;
  }
}

// ---------------------------------------------------------------------------
// QKV GEMM, 4-phase fine interleave: X[4096][1024] x Wqkv[3072][1024]^T,
// tile 256x256, BK=64, 16 K-tiles. 512 thr = 8 waves (2M x 4N), per-wave
// 128x64 out. LDS 128KB: A[2][256][128B] + B[2][256][128B], XOR-swizzled.
// Per K-tile 4 phases, each {ds_read subset | stage 1 half-tile | barrier |
// lgkmcnt(0) | 16 MFMA | barrier}. Stage slots: P0/P1 = A-halves of t+1,
// P2/P3 = B-halves of t+2. vmcnt(4) once per tile boundary (0 before last).
// ---------------------------------------------------------------------------
__global__ __launch_bounds__(512, 2) void qkv_gemm_kernel(
    const u16* __restrict__ Xb, const u16* __restrict__ Wb,
    u16* __restrict__ Qws, u16* __restrict__ Kws, u16* __restrict__ Vtws,
    float* __restrict__ out) {
  extern __shared__ char smem[];   // A: [2][32KB] @0; B: [2][32KB] @65536

  const int tid = threadIdx.x, lane = tid & 63, wid = tid >> 6;
  const int wr = wid >> 2, wc = wid & 3;
  const int fq = lane >> 4, fr = lane & 15;

  const int wg = (blockIdx.x & 7) * 24 + (blockIdx.x >> 3);
  const int bm = wg / 12, bn = wg % 12;
  const int m0 = bm * 256, n0 = bn * 256;

  const char* Ab = (const char*)Xb + (size_t)m0 * 2048;
  const char* Bb = (const char*)Wb + (size_t)n0 * 2048;

  f32x4 acc[8][4] = {};

  // stage one half-tile (128 rows x 64 cols = 16KB): 2 gload_lds per thread
  auto stage_half = [&](int t, int mat, int h) {
    char* dst = smem + mat * 65536 + (t & 1) * 32768 + h * 16384;
    const char* src = mat ? Bb : Ab;
#pragma unroll
    for (int l = 0; l < 2; ++l) {
      int lin = (l * 512 + tid) * 16;          // 0..16383
      int rl  = lin >> 7;                      // local row 0..127
      int col = (lin & 127) ^ ((rl & 7) << 4); // inverse-swizzled source
      gload_lds16(src + (size_t)(h * 128 + rl) * 2048 + t * 128 + col, dst + lin);
    }
  };

  // prologue: tile0 A+B halves, tile1 B halves (tile1 A staged in t0 P0/P1)
  stage_half(0, 0, 0); stage_half(0, 0, 1);
  stage_half(0, 1, 0); stage_half(0, 1, 1);
  stage_half(1, 1, 0); stage_half(1, 1, 1);
  asm volatile("s_waitcnt vmcnt(4)" ::: "memory");   // tile0's 8 loads done
  __builtin_amdgcn_s_barrier();

  bf16x8 afr[4][2];   // current m-set (4 m x 2 ks)
  bf16x8 bfr[4][2];   // all 4 n x 2 ks

  for (int t = 0; t < 16; ++t) {
    const char* As = smem + (t & 1) * 32768;
    const char* Bs = smem + 65536 + (t & 1) * 32768;

    // ---------- P0: read A m0-3 + B n0-1; stage Ah0(t+1); MFMA m0-3 x n0-1
#pragma unroll
    for (int m = 0; m < 4; ++m) {
      int row = wr * 128 + m * 16 + fr;
#pragma unroll
      for (int ks = 0; ks < 2; ++ks)
        afr[m][ks] = *(const bf16x8*)(As + row * 128 + ((ks * 64 + fq * 16) ^ ((row & 7) << 4)));
    }
#pragma unroll
    for (int n = 0; n < 2; ++n) {
      int row = wc * 64 + n * 16 + fr;
#pragma unroll
      for (int ks = 0; ks < 2; ++ks)
        bfr[n][ks] = *(const bf16x8*)(Bs + row * 128 + ((ks * 64 + fq * 16) ^ ((row & 7) << 4)));
    }
    if (t + 1 < 16) stage_half(t + 1, 0, 0);
    __builtin_amdgcn_s_barrier();
    asm volatile("s_waitcnt lgkmcnt(0)" ::: "memory");
    __builtin_amdgcn_sched_barrier(0);
    __builtin_amdgcn_s_setprio(1);
#pragma unroll
    for (int m = 0; m < 4; ++m)
#pragma unroll
      for (int n = 0; n < 2; ++n)
#pragma unroll
        for (int ks = 0; ks < 2; ++ks)
          acc[m][n] = __builtin_amdgcn_mfma_f32_16x16x32_bf16(afr[m][ks], bfr[n][ks], acc[m][n], 0, 0, 0);
    __builtin_amdgcn_s_setprio(0);
    __builtin_amdgcn_s_barrier();

    // ---------- P1: read B n2-3; stage Ah1(t+1); MFMA m0-3 x n2-3
#pragma unroll
    for (int n = 2; n < 4; ++n) {
      int row = wc * 64 + n * 16 + fr;
#pragma unroll
      for (int ks = 0; ks < 2; ++ks)
        bfr[n][ks] = *(const bf16x8*)(Bs + row * 128 + ((ks * 64 + fq * 16) ^ ((row & 7) << 4)));
    }
    if (t + 1 < 16) stage_half(t + 1, 0, 1);
    __builtin_amdgcn_s_barrier();
    asm volatile("s_waitcnt lgkmcnt(0)" ::: "memory");
    __builtin_amdgcn_sched_barrier(0);
    __builtin_amdgcn_s_setprio(1);
#pragma unroll
    for (int m = 0; m < 4; ++m)
#pragma unroll
      for (int n = 2; n < 4; ++n)
#pragma unroll
        for (int ks = 0; ks < 2; ++ks)
          acc[m][n] = __builtin_amdgcn_mfma_f32_16x16x32_bf16(afr[m][ks], bfr[n][ks], acc[m][n], 0, 0, 0);
    __builtin_amdgcn_s_setprio(0);
    __builtin_amdgcn_s_barrier();

    // ---------- P2: read A m4-7 (reuse afr); stage Bh0(t+2); MFMA m4-7 x n0-1
#pragma unroll
    for (int m = 0; m < 4; ++m) {
      int row = wr * 128 + (m + 4) * 16 + fr;
#pragma unroll
      for (int ks = 0; ks < 2; ++ks)
        afr[m][ks] = *(const bf16x8*)(As + row * 128 + ((ks * 64 + fq * 16) ^ ((row & 7) << 4)));
    }
    if (t + 2 < 16) stage_half(t + 2, 1, 0);
    __builtin_amdgcn_s_barrier();
    asm volatile("s_waitcnt lgkmcnt(0)" ::: "memory");
    __builtin_amdgcn_sched_barrier(0);
    __builtin_amdgcn_s_setprio(1);
#pragma unroll
    for (int m = 0; m < 4; ++m)
#pragma unroll
      for (int n = 0; n < 2; ++n)
#pragma unroll
        for (int ks = 0; ks < 2; ++ks)
          acc[m + 4][n] = __builtin_amdgcn_mfma_f32_16x16x32_bf16(afr[m][ks], bfr[n][ks], acc[m + 4][n], 0, 0, 0);
    __builtin_amdgcn_s_setprio(0);
    __builtin_amdgcn_s_barrier();

    // ---------- P3: stage Bh1(t+2); MFMA m4-7 x n2-3; tile-boundary vmcnt
    if (t + 2 < 16) stage_half(t + 2, 1, 1);
    __builtin_amdgcn_s_barrier();
    __builtin_amdgcn_s_setprio(1);
#pragma unroll
    for (int m = 0; m < 4; ++m)
#pragma unroll
      for (int n = 2; n < 4; ++n)
#pragma unroll
        for (int ks = 0; ks < 2; ++ks)
          acc[m + 4][n] = __builtin_amdgcn_mfma_f32_16x16x32_bf16(afr[m][ks], bfr[n][ks], acc[m + 4][n], 0, 0, 0);
    __builtin_amdgcn_s_setprio(0);
    if (t < 15) {
      if (t == 14) asm volatile("s_waitcnt vmcnt(0)" ::: "memory");
      else         asm volatile("s_waitcnt vmcnt(4)" ::: "memory");
    }
    __builtin_amdgcn_s_barrier();
  }

  // ---- epilogue (validated r6/r9): Q pre-scaled bf16; K bf16+fp32; V fp32+V^T
  const int sect = n0 >> 10;
  const int nn0 = (n0 & 1023) + wc * 64;
  const int mbase = m0 + wr * 128;
#pragma unroll
  for (int m = 0; m < 8; ++m)
#pragma unroll
    for (int n = 0; n < 4; ++n) {
      int mB = mbase + m * 16 + fq * 4;
      int ncol = nn0 + n * 16 + fr;
      int b = mB >> 11, s0 = mB & 2047;
      int h = ncol >> 6, hd = ncol & 63;
      size_t base = (((size_t)b * 16 + h) * 2048 + s0) * 64 + hd;
      float v0 = acc[m][n][0], v1 = acc[m][n][1], v2 = acc[m][n][2], v3 = acc[m][n][3];
      if (sect == 0) {
        Qws[base]       = f2bf(v0 * SOFT_SCALE);
        Qws[base + 64]  = f2bf(v1 * SOFT_SCALE);
        Qws[base + 128] = f2bf(v2 * SOFT_SCALE);
        Qws[base + 192] = f2bf(v3 * SOFT_SCALE);
      } else if (sect == 1) {
        Kws[base] = f2bf(v0); Kws[base + 64] = f2bf(v1);
        Kws[base + 128] = f2bf(v2); Kws[base + 192] = f2bf(v3);
        out[4194304 + base] = v0; out[4194304 + base + 64] = v1;
        out[4194304 + base + 128] = v2; out[4194304 + base + 192] = v3;
      } else {
        out[8388608 + base] = v0; out[8388608 + base + 64] = v1;
        out[8388608 + base + 128] = v2; out[8388608 + base + 192] = v3;
        size_t tt = ((size_t)(b * 16 + h) * 64 + hd) * 2048 + s0;
        ushort4 pk; pk.x = f2bf(v0); pk.y = f2bf(v1); pk.z = f2bf(v2); pk.w = f2bf(v3);
        *reinterpret_cast<ushort4*>(Vtws + tt) = pk;
      }
    }
}

// ---------------------------------------------------------------------------
// 128x128 tile GEMM core (m97 structure) — used by proj only.
// ---------------------------------------------------------------------------
__device__ __forceinline__ void gemm128_core(const u16* __restrict__ A,
                                             const u16* __restrict__ B,
                                             int m0, int n0, int K,
                                             u16* As, u16* Bs, f32x4 acc[4][4]) {
  const int tid  = threadIdx.x;
  const int lane = tid & 63;
  const int wid  = tid >> 6;
  const int wr = wid >> 1, wc = wid & 1;
  const int fq = lane >> 4, fr = lane & 15;

  for (int kb = 0; kb < K; kb += 32) {
#pragma unroll
    for (int j = 0; j < 2; ++j) {
      int lin = (j * 256 + tid) * 16;
      int row = lin >> 6;
      int rb  = lin & 63;
      gload_lds16((const char*)(A + (size_t)(m0 + row) * K + kb) + rb, (char*)As + lin);
      gload_lds16((const char*)(B + (size_t)(n0 + row) * K + kb) + rb, (char*)Bs + lin);
    }
    __syncthreads();

    bf16x8 av[4], bv[4];
#pragma unroll
    for (int i = 0; i < 4; ++i) av[i] = ldfrag(As + (wr * 64 + i * 16 + fr) * 32 + fq * 8);
#pragma unroll
    for (int j = 0; j < 4; ++j) bv[j] = ldfrag(Bs + (wc * 64 + j * 16 + fr) * 32 + fq * 8);
    __builtin_amdgcn_s_setprio(1);
#pragma unroll
    for (int i = 0; i < 4; ++i)
#pragma unroll
      for (int j = 0; j < 4; ++j)
        acc[i][j] = __builtin_amdgcn_mfma_f32_16x16x32_bf16(av[i], bv[j], acc[i][j], 0, 0, 0);
    __builtin_amdgcn_s_setprio(0);
    __syncthreads();
  }
}

// ---------------------------------------------------------------------------
// Flash causal attention (r10, proven 46.2us). grid = 1024; block = 256.
// QBLK=64, KVBLK=64, [64][64] XOR-swizzled K/V^T dbuf, swapped QK^T,
// cvt_pk + permlane32/16_swap in-register P, no-max softmax, scalar ssum.
// ---------------------------------------------------------------------------
__global__ __launch_bounds__(256, 4) void attn_kernel(
    const u16* __restrict__ Qw, const u16* __restrict__ Kw,
    const u16* __restrict__ Vtw, u16* __restrict__ Ow) {
  __shared__ u16 Ks[2][64 * 64];
  __shared__ u16 Vs[2][64 * 64];

  const int tid = threadIdx.x, lane = tid & 63, wid = tid >> 6;
  const int fq = lane >> 4, fr = lane & 15;
  const int bh = blockIdx.x & 31;
  const int qb = 31 - (blockIdx.x >> 5);   // heavy blocks first
  const int b = bh >> 4, h = bh & 15;
  const int q0 = qb * 64;

  const u16* Qbase  = Qw  + (size_t)bh * 2048 * 64;
  const u16* Kbase  = Kw  + (size_t)bh * 2048 * 64;
  const char* VtBase = (const char*)(Vtw + (size_t)bh * 64 * 2048);

#pragma unroll
  for (int f = 0; f < 2; ++f) {
    int lin = (f * 256 + tid) * 16;
    int row = lin >> 7;
    int logical = lin ^ ((row & 7) << 4);
    gload_lds16((const char*)Kbase + logical, (char*)Ks[0] + lin);
    gload_lds16(VtBase + (size_t)row * 4096 + (logical & 127), (char*)Vs[0] + lin);
  }

  const int qrow = q0 + wid * 16 + fr;
  bf16x8 qa0 = ldfrag(Qbase + (size_t)qrow * 64 + fq * 8);
  bf16x8 qa1 = ldfrag(Qbase + (size_t)qrow * 64 + 32 + fq * 8);

  float ssum = 0.f;
  f32x4 accO[4] = {};

  int cur = 0;
  for (int kb = 0; kb <= qb; ++kb) {
    __syncthreads();

    if (kb < qb) {
      const char* kg = (const char*)(Kbase + (size_t)(kb + 1) * 64 * 64);
#pragma unroll
      for (int f = 0; f < 2; ++f) {
        int lin = (f * 256 + tid) * 16;
        int row = lin >> 7;
        int logical = lin ^ ((row & 7) << 4);
        gload_lds16(kg + logical, (char*)Ks[cur ^ 1] + lin);
        gload_lds16(VtBase + (size_t)row * 4096 + (size_t)(kb + 1) * 128 + (logical & 127),
                    (char*)Vs[cur ^ 1] + lin);
      }
    }

    const u16* Kc = Ks[cur];
    const u16* Vc = Vs[cur];

    f32x4 sfr[4];
    __builtin_amdgcn_s_setprio(1);
#pragma unroll
    for (int n = 0; n < 4; ++n) {
      int krow = n * 16 + fr;
      bf16x8 kf0 = ldfrag(Kc + krow * 64 + ((fq * 8)      ^ ((krow & 7) << 3)));
      bf16x8 kf1 = ldfrag(Kc + krow * 64 + ((fq * 8 + 32) ^ ((krow & 7) << 3)));
      f32x4 z = {};
      z = __builtin_amdgcn_mfma_f32_16x16x32_bf16(kf0, qa0, z, 0, 0, 0);
      z = __builtin_amdgcn_mfma_f32_16x16x32_bf16(kf1, qa1, z, 0, 0, 0);
      sfr[n] = z;
    }
    __builtin_amdgcn_s_setprio(0);

    uint32_t W[4][2];
#pragma unroll
    for (int n = 0; n < 4; ++n) {
      float p0, p1, p2, p3;
      if (kb < qb) {
        p0 = exp2f(sfr[n][0]);
        p1 = exp2f(sfr[n][1]);
        p2 = exp2f(sfr[n][2]);
        p3 = exp2f(sfr[n][3]);
      } else {
        int kvg = kb * 64 + n * 16 + fq * 4;
        p0 = (kvg + 0 > qrow) ? 0.f : exp2f(sfr[n][0]);
        p1 = (kvg + 1 > qrow) ? 0.f : exp2f(sfr[n][1]);
        p2 = (kvg + 2 > qrow) ? 0.f : exp2f(sfr[n][2]);
        p3 = (kvg + 3 > qrow) ? 0.f : exp2f(sfr[n][3]);
      }
      ssum += (p0 + p1) + (p2 + p3);
      W[n][0] = cvt_pk_bf16(p0, p1);
      W[n][1] = cvt_pk_bf16(p2, p3);
    }

    union { uint32_t u[4]; bf16x8 v; } pa0u, pa1u;
#pragma unroll
    for (int hh = 0; hh < 2; ++hh) {
      uint32_t a0 = W[0][hh], b0 = W[1][hh];
      asm("v_permlane32_swap_b32 %0, %1" : "+v"(a0), "+v"(b0));
      asm("v_permlane16_swap_b32 %0, %1" : "+v"(a0), "+v"(b0));
      pa0u.u[hh] = a0; pa0u.u[2 + hh] = b0;
      uint32_t a1 = W[2][hh], b1 = W[3][hh];
      asm("v_permlane32_swap_b32 %0, %1" : "+v"(a1), "+v"(b1));
      asm("v_permlane16_swap_b32 %0, %1" : "+v"(a1), "+v"(b1));
      pa1u.u[hh] = a1; pa1u.u[2 + hh] = b1;
    }

    __builtin_amdgcn_s_setprio(1);
#pragma unroll
    for (int nh = 0; nh < 4; ++nh) {
      int vrow = nh * 16 + fr;
      bf16x8 vb0 = ldfrag(Vc + vrow * 64 + ((fq * 8)      ^ ((vrow & 7) << 3)));
      bf16x8 vb1 = ldfrag(Vc + vrow * 64 + ((fq * 8 + 32) ^ ((vrow & 7) << 3)));
      accO[nh] = __builtin_amdgcn_mfma_f32_16x16x32_bf16(pa0u.v, vb0, accO[nh], 0, 0, 0);
      accO[nh] = __builtin_amdgcn_mfma_f32_16x16x32_bf16(pa1u.v, vb1, accO[nh], 0, 0, 0);
    }
    __builtin_amdgcn_s_setprio(0);
    cur ^= 1;
  }

  ssum += __shfl_xor(ssum, 16);
  ssum += __shfl_xor(ssum, 32);
  float inv = 1.0f / ssum;
  float invq[4];
#pragma unroll
  for (int r = 0; r < 4; ++r) invq[r] = __shfl(inv, fq * 4 + r);

#pragma unroll
  for (int nh = 0; nh < 4; ++nh)
#pragma unroll
    for (int r = 0; r < 4; ++r) {
      float o = accO[nh][r] * invq[r];
      int qr = q0 + wid * 16 + fq * 4 + r;
      Ow[((size_t)b * 2048 + qr) * 1024 + h * 64 + nh * 16 + fr] = f2bf(o);
    }
}

// ---------------------------------------------------------------------------
// Output projection: O[4096][1024] x Wo[1024][1024]^T + b -> y fp32
// ---------------------------------------------------------------------------
__global__ __launch_bounds__(256) void proj_gemm_kernel(
    const u16* __restrict__ Ob, const u16* __restrict__ Wob,
    const float* __restrict__ bias, float* __restrict__ out) {
  __shared__ u16 As[128 * 32];
  __shared__ u16 Bs[128 * 32];
  const int NB = 8;
  int m0 = (blockIdx.x / NB) * 128, n0 = (blockIdx.x % NB) * 128;
  f32x4 acc[4][4] = {};
  gemm128_core(Ob, Wob, m0, n0, 1024, As, Bs, acc);

  const int lane = threadIdx.x & 63, wid = threadIdx.x >> 6;
  const int wr = wid >> 1, wc = wid & 1, fq = lane >> 4, fr = lane & 15;
#pragma unroll
  for (int i = 0; i < 4; ++i)
#pragma unroll
    for (int j = 0; j < 4; ++j)
#pragma unroll
      for (int r = 0; r < 4; ++r) {
        int m = m0 + wr * 64 + i * 16 + fq * 4 + r;
        int n = n0 + wc * 64 + j * 16 + fr;
        out[(size_t)m * 1024 + n] = acc[i][j][r] + bias[n];
      }
}

// ---------------------------------------------------------------------------
extern "C" void kernel_launch(void* const* d_in, const int* in_sizes, int n_in,
                              void* d_out, int out_size, void* d_ws, size_t ws_size,
                              hipStream_t stream) {
  const float* x    = (const float*)d_in[0];
  const float* wqkv = (const float*)d_in[1];
  const float* wo   = (const float*)d_in[2];
  const float* wo_b = (const float*)d_in[3];
  float* out = (float*)d_out;

  u16* xb    = (u16*)d_ws;            // 4096*1024
  u16* wqkvb = xb    + 4194304;       // 3072*1024
  u16* wob   = wqkvb + 3145728;       // 1024*1024
  u16* q_ws  = wob   + 1048576;       // [2,16,2048,64] (pre-scaled)
  u16* k_ws  = q_ws  + 4194304;       // [2,16,2048,64]
  u16* vt_ws = k_ws  + 4194304;       // [2,16,64,2048]  (V^T)
  u16* o_ws  = vt_ws + 4194304;       // [4096,1024]

  static bool attr_set = false;
  if (!attr_set) {
    hipFuncSetAttribute((const void*)qkv_gemm_kernel,
                        hipFuncAttributeMaxDynamicSharedMemorySize, 131072);
    attr_set = true;
  }

  cvt_all<<<2048, 256, 0, stream>>>(x, wqkv, wo, xb, wqkvb, wob);
  qkv_gemm_kernel<<<192, 512, 131072, stream>>>(xb, wqkvb, q_ws, k_ws, vt_ws, out);
  attn_kernel<<<32 * 32, 256, 0, stream>>>(q_ws, k_ws, vt_ws, o_ws);
  proj_gemm_kernel<<<32 * 8, 256, 0, stream>>>(o_ws, wob, wo_b, out);
}

// Round 13
// 116.465 us; speedup vs baseline: 1.0617x; 1.0116x over previous
//
#include <hip/hip_runtime.h>
#include <cstdint>
#include <cstddef>

// ---------------------------------------------------------------------------
// MHA forward: x[2,2048,1024] fp32, wqkv[3072,1024], wo[1024,1024], wo_b[1024]
// out = concat(y[2,2048,1024], k[2,16,2048,64], v[2,16,2048,64]) fp32
// Pipeline: cvt->bf16 (fused); QKV GEMM (256x256 4-phase, counted vmcnt, Q
// pre-scaled); flash causal attn (waves partitioned kv-half x q-half: halves
// LDS read redundancy; swapped QK^T + permlane in-reg P; end-only cross-wave
// reduce); proj GEMM (128x128 m97-structure).
// ---------------------------------------------------------------------------

using bf16x8 = __attribute__((ext_vector_type(8))) __bf16;
using f32x4  = __attribute__((ext_vector_type(4))) float;
using u16    = unsigned short;

#define SOFT_SCALE 0.1803368801111244f   // 0.125 * log2(e)  (attn in exp2 domain)

// fp32 -> bf16 bits, round-to-nearest-even
__device__ __forceinline__ u16 f2bf(float f) {
  union { float f; uint32_t u; } a; a.f = f;
  uint32_t r = a.u + 0x7fffu + ((a.u >> 16) & 1u);
  return (u16)(r >> 16);
}

__device__ __forceinline__ bf16x8 ldfrag(const u16* p) {
  return *reinterpret_cast<const bf16x8*>(p);
}

__device__ __forceinline__ void gload_lds16(const void* g, void* l) {
  __builtin_amdgcn_global_load_lds((const __attribute__((address_space(1))) void*)g,
                                   (__attribute__((address_space(3))) void*)l,
                                   16, 0, 0);
}

// pack two fp32 -> one u32 of two bf16 (lo = a, hi = b), RNE
__device__ __forceinline__ uint32_t cvt_pk_bf16(float a, float b) {
  uint32_t r;
  asm("v_cvt_pk_bf16_f32 %0, %1, %2" : "=v"(r) : "v"(a), "v"(b));
  return r;
}

// ---------------------------------------------------------------------------
// fused fp32 -> bf16 convert for x, wqkv, wo (single launch)
// ---------------------------------------------------------------------------
__global__ void cvt_all(const float* __restrict__ x, const float* __restrict__ wqkv,
                        const float* __restrict__ wo,
                        u16* __restrict__ xb, u16* __restrict__ wqkvb, u16* __restrict__ wob) {
  int i = blockIdx.x * blockDim.x + threadIdx.x;
  int stride = gridDim.x * blockDim.x;
  for (; i < 2097152; i += stride) {
    const float* src; u16* dst; int j;
    if (i < 1048576)      { src = x;    dst = xb;    j = i; }
    else if (i < 1835008) { src = wqkv; dst = wqkvb; j = i - 1048576; }
    else                  { src = wo;   dst = wob;   j = i - 1835008; }
    float4 v = reinterpret_cast<const float4*>(src)[j];
    ushort4 o;
    o.x = f2bf(v.x); o.y = f2bf(v.y); o.z = f2bf(v.z); o.w = f2bf(v.w);
    reinterpret_cast<ushort4*>(dst)[j] = o;
  }
}

// ---------------------------------------------------------------------------
// QKV GEMM, 4-phase fine interleave (r12). 256x256 tile, BK=64, 16 K-tiles.
// ---------------------------------------------------------------------------
__global__ __launch_bounds__(512, 2) void qkv_gemm_kernel(
    const u16* __restrict__ Xb, const u16* __restrict__ Wb,
    u16* __restrict__ Qws, u16* __restrict__ Kws, u16* __restrict__ Vtws,
    float* __restrict__ out) {
  extern __shared__ char smem[];   // A: [2][32KB] @0; B: [2][32KB] @65536

  const int tid = threadIdx.x, lane = tid & 63, wid = tid >> 6;
  const int wr = wid >> 2, wc = wid & 3;
  const int fq = lane >> 4, fr = lane & 15;

  const int wg = (blockIdx.x & 7) * 24 + (blockIdx.x >> 3);
  const int bm = wg / 12, bn = wg % 12;
  const int m0 = bm * 256, n0 = bn * 256;

  const char* Ab = (const char*)Xb + (size_t)m0 * 2048;
  const char* Bb = (const char*)Wb + (size_t)n0 * 2048;

  f32x4 acc[8][4] = {};

  auto stage_half = [&](int t, int mat, int h) {
    char* dst = smem + mat * 65536 + (t & 1) * 32768 + h * 16384;
    const char* src = mat ? Bb : Ab;
#pragma unroll
    for (int l = 0; l < 2; ++l) {
      int lin = (l * 512 + tid) * 16;
      int rl  = lin >> 7;
      int col = (lin & 127) ^ ((rl & 7) << 4);
      gload_lds16(src + (size_t)(h * 128 + rl) * 2048 + t * 128 + col, dst + lin);
    }
  };

  stage_half(0, 0, 0); stage_half(0, 0, 1);
  stage_half(0, 1, 0); stage_half(0, 1, 1);
  stage_half(1, 1, 0); stage_half(1, 1, 1);
  asm volatile("s_waitcnt vmcnt(4)" ::: "memory");
  __builtin_amdgcn_s_barrier();

  bf16x8 afr[4][2];
  bf16x8 bfr[4][2];

  for (int t = 0; t < 16; ++t) {
    const char* As = smem + (t & 1) * 32768;
    const char* Bs = smem + 65536 + (t & 1) * 32768;

#pragma unroll
    for (int m = 0; m < 4; ++m) {
      int row = wr * 128 + m * 16 + fr;
#pragma unroll
      for (int ks = 0; ks < 2; ++ks)
        afr[m][ks] = *(const bf16x8*)(As + row * 128 + ((ks * 64 + fq * 16) ^ ((row & 7) << 4)));
    }
#pragma unroll
    for (int n = 0; n < 2; ++n) {
      int row = wc * 64 + n * 16 + fr;
#pragma unroll
      for (int ks = 0; ks < 2; ++ks)
        bfr[n][ks] = *(const bf16x8*)(Bs + row * 128 + ((ks * 64 + fq * 16) ^ ((row & 7) << 4)));
    }
    if (t + 1 < 16) stage_half(t + 1, 0, 0);
    __builtin_amdgcn_s_barrier();
    asm volatile("s_waitcnt lgkmcnt(0)" ::: "memory");
    __builtin_amdgcn_sched_barrier(0);
    __builtin_amdgcn_s_setprio(1);
#pragma unroll
    for (int m = 0; m < 4; ++m)
#pragma unroll
      for (int n = 0; n < 2; ++n)
#pragma unroll
        for (int ks = 0; ks < 2; ++ks)
          acc[m][n] = __builtin_amdgcn_mfma_f32_16x16x32_bf16(afr[m][ks], bfr[n][ks], acc[m][n], 0, 0, 0);
    __builtin_amdgcn_s_setprio(0);
    __builtin_amdgcn_s_barrier();

#pragma unroll
    for (int n = 2; n < 4; ++n) {
      int row = wc * 64 + n * 16 + fr;
#pragma unroll
      for (int ks = 0; ks < 2; ++ks)
        bfr[n][ks] = *(const bf16x8*)(Bs + row * 128 + ((ks * 64 + fq * 16) ^ ((row & 7) << 4)));
    }
    if (t + 1 < 16) stage_half(t + 1, 0, 1);
    __builtin_amdgcn_s_barrier();
    asm volatile("s_waitcnt lgkmcnt(0)" ::: "memory");
    __builtin_amdgcn_sched_barrier(0);
    __builtin_amdgcn_s_setprio(1);
#pragma unroll
    for (int m = 0; m < 4; ++m)
#pragma unroll
      for (int n = 2; n < 4; ++n)
#pragma unroll
        for (int ks = 0; ks < 2; ++ks)
          acc[m][n] = __builtin_amdgcn_mfma_f32_16x16x32_bf16(afr[m][ks], bfr[n][ks], acc[m][n], 0, 0, 0);
    __builtin_amdgcn_s_setprio(0);
    __builtin_amdgcn_s_barrier();

#pragma unroll
    for (int m = 0; m < 4; ++m) {
      int row = wr * 128 + (m + 4) * 16 + fr;
#pragma unroll
      for (int ks = 0; ks < 2; ++ks)
        afr[m][ks] = *(const bf16x8*)(As + row * 128 + ((ks * 64 + fq * 16) ^ ((row & 7) << 4)));
    }
    if (t + 2 < 16) stage_half(t + 2, 1, 0);
    __builtin_amdgcn_s_barrier();
    asm volatile("s_waitcnt lgkmcnt(0)" ::: "memory");
    __builtin_amdgcn_sched_barrier(0);
    __builtin_amdgcn_s_setprio(1);
#pragma unroll
    for (int m = 0; m < 4; ++m)
#pragma unroll
      for (int n = 0; n < 2; ++n)
#pragma unroll
        for (int ks = 0; ks < 2; ++ks)
          acc[m + 4][n] = __builtin_amdgcn_mfma_f32_16x16x32_bf16(afr[m][ks], bfr[n][ks], acc[m + 4][n], 0, 0, 0);
    __builtin_amdgcn_s_setprio(0);
    __builtin_amdgcn_s_barrier();

    if (t + 2 < 16) stage_half(t + 2, 1, 1);
    __builtin_amdgcn_s_barrier();
    __builtin_amdgcn_s_setprio(1);
#pragma unroll
    for (int m = 0; m < 4; ++m)
#pragma unroll
      for (int n = 2; n < 4; ++n)
#pragma unroll
        for (int ks = 0; ks < 2; ++ks)
          acc[m + 4][n] = __builtin_amdgcn_mfma_f32_16x16x32_bf16(afr[m][ks], bfr[n][ks], acc[m + 4][n], 0, 0, 0);
    __builtin_amdgcn_s_setprio(0);
    if (t < 15) {
      if (t == 14) asm volatile("s_waitcnt vmcnt(0)" ::: "memory");
      else         asm volatile("s_waitcnt vmcnt(4)" ::: "memory");
    }
    __builtin_amdgcn_s_barrier();
  }

  const int sect = n0 >> 10;
  const int nn0 = (n0 & 1023) + wc * 64;
  const int mbase = m0 + wr * 128;
#pragma unroll
  for (int m = 0; m < 8; ++m)
#pragma unroll
    for (int n = 0; n < 4; ++n) {
      int mB = mbase + m * 16 + fq * 4;
      int ncol = nn0 + n * 16 + fr;
      int b = mB >> 11, s0 = mB & 2047;
      int h = ncol >> 6, hd = ncol & 63;
      size_t base = (((size_t)b * 16 + h) * 2048 + s0) * 64 + hd;
      float v0 = acc[m][n][0], v1 = acc[m][n][1], v2 = acc[m][n][2], v3 = acc[m][n][3];
      if (sect == 0) {
        Qws[base]       = f2bf(v0 * SOFT_SCALE);
        Qws[base + 64]  = f2bf(v1 * SOFT_SCALE);
        Qws[base + 128] = f2bf(v2 * SOFT_SCALE);
        Qws[base + 192] = f2bf(v3 * SOFT_SCALE);
      } else if (sect == 1) {
        Kws[base] = f2bf(v0); Kws[base + 64] = f2bf(v1);
        Kws[base + 128] = f2bf(v2); Kws[base + 192] = f2bf(v3);
        out[4194304 + base] = v0; out[4194304 + base + 64] = v1;
        out[4194304 + base + 128] = v2; out[4194304 + base + 192] = v3;
      } else {
        out[8388608 + base] = v0; out[8388608 + base + 64] = v1;
        out[8388608 + base + 128] = v2; out[8388608 + base + 192] = v3;
        size_t tt = ((size_t)(b * 16 + h) * 64 + hd) * 2048 + s0;
        ushort4 pk; pk.x = f2bf(v0); pk.y = f2bf(v1); pk.z = f2bf(v2); pk.w = f2bf(v3);
        *reinterpret_cast<ushort4*>(Vtws + tt) = pk;
      }
    }
}

// ---------------------------------------------------------------------------
// 128x128 tile GEMM core (m97 structure) — used by proj only.
// ---------------------------------------------------------------------------
__device__ __forceinline__ void gemm128_core(const u16* __restrict__ A,
                                             const u16* __restrict__ B,
                                             int m0, int n0, int K,
                                             u16* As, u16* Bs, f32x4 acc[4][4]) {
  const int tid  = threadIdx.x;
  const int lane = tid & 63;
  const int wid  = tid >> 6;
  const int wr = wid >> 1, wc = wid & 1;
  const int fq = lane >> 4, fr = lane & 15;

  for (int kb = 0; kb < K; kb += 32) {
#pragma unroll
    for (int j = 0; j < 2; ++j) {
      int lin = (j * 256 + tid) * 16;
      int row = lin >> 6;
      int rb  = lin & 63;
      gload_lds16((const char*)(A + (size_t)(m0 + row) * K + kb) + rb, (char*)As + lin);
      gload_lds16((const char*)(B + (size_t)(n0 + row) * K + kb) + rb, (char*)Bs + lin);
    }
    __syncthreads();

    bf16x8 av[4], bv[4];
#pragma unroll
    for (int i = 0; i < 4; ++i) av[i] = ldfrag(As + (wr * 64 + i * 16 + fr) * 32 + fq * 8);
#pragma unroll
    for (int j = 0; j < 4; ++j) bv[j] = ldfrag(Bs + (wc * 64 + j * 16 + fr) * 32 + fq * 8);
    __builtin_amdgcn_s_setprio(1);
#pragma unroll
    for (int i = 0; i < 4; ++i)
#pragma unroll
      for (int j = 0; j < 4; ++j)
        acc[i][j] = __builtin_amdgcn_mfma_f32_16x16x32_bf16(av[i], bv[j], acc[i][j], 0, 0, 0);
    __builtin_amdgcn_s_setprio(0);
    __syncthreads();
  }
}

// ---------------------------------------------------------------------------
// Flash causal attention. grid = 1024; block = 256 (4 waves).
// Wave (wk,wh) owns kv-half wk (32 rows) x q-half wh (32 rows): each wave
// reads only HALF of K and V^T per tile (8KB vs 16KB) -> 2x less LDS-read BW.
// Q hoisted (4 B-frags). Swapped QK^T -> lane-local P; permlane per q-tile.
// PV native K=32. Cross-wk O/ssum reduce ONCE at end via dead Ks/Vs LDS.
// No-max softmax (Q pre-scaled), heavy-first grid.
// ---------------------------------------------------------------------------
__global__ __launch_bounds__(256, 4) void attn_kernel(
    const u16* __restrict__ Qw, const u16* __restrict__ Kw,
    const u16* __restrict__ Vtw, u16* __restrict__ Ow) {
  __shared__ u16 Ks[2][64 * 64];
  __shared__ u16 Vs[2][64 * 64];

  const int tid = threadIdx.x, lane = tid & 63, wid = tid >> 6;
  const int wk = wid >> 1, wh = wid & 1;
  const int fq = lane >> 4, fr = lane & 15;
  const int bh = blockIdx.x & 31;
  const int qb = 31 - (blockIdx.x >> 5);   // heavy blocks first
  const int b = bh >> 4, h = bh & 15;
  const int q0 = qb * 64;

  const u16* Qbase  = Qw  + (size_t)bh * 2048 * 64;
  const u16* Kbase  = Kw  + (size_t)bh * 2048 * 64;
  const char* VtBase = (const char*)(Vtw + (size_t)bh * 64 * 2048);

  // ---- prologue: stage KV tile 0 (inverse-swizzled source)
#pragma unroll
  for (int f = 0; f < 2; ++f) {
    int lin = (f * 256 + tid) * 16;
    int row = lin >> 7;
    int logical = lin ^ ((row & 7) << 4);
    gload_lds16((const char*)Kbase + logical, (char*)Ks[0] + lin);
    gload_lds16(VtBase + (size_t)row * 4096 + (logical & 127), (char*)Vs[0] + lin);
  }

  // ---- hoisted Q B-frags: q = q0 + wh*32 + qt*16 + fr  (pre-scaled)
  bf16x8 qa[2][2];   // [qt][kh]
#pragma unroll
  for (int qt = 0; qt < 2; ++qt)
#pragma unroll
    for (int kh = 0; kh < 2; ++kh)
      qa[qt][kh] = ldfrag(Qbase + (size_t)(q0 + wh * 32 + qt * 16 + fr) * 64 + kh * 32 + fq * 8);

  float ssum[2] = {0.f, 0.f};   // per qt, q = q0 + wh*32 + qt*16 + fr
  f32x4 accO[2][4] = {};        // [qt][ht]

  int cur = 0;
  for (int kb = 0; kb <= qb; ++kb) {
    __syncthreads();   // buf[cur] staged; all waves past prev reads

    if (kb < qb) {
      const char* kg = (const char*)(Kbase + (size_t)(kb + 1) * 64 * 64);
#pragma unroll
      for (int f = 0; f < 2; ++f) {
        int lin = (f * 256 + tid) * 16;
        int row = lin >> 7;
        int logical = lin ^ ((row & 7) << 4);
        gload_lds16(kg + logical, (char*)Ks[cur ^ 1] + lin);
        gload_lds16(VtBase + (size_t)row * 4096 + (size_t)(kb + 1) * 128 + (logical & 127),
                    (char*)Vs[cur ^ 1] + lin);
      }
    }

    const u16* Kc = Ks[cur];
    const u16* Vc = Vs[cur];

    // ---- S^T = K Q^T over wave's kv-half x q-half: 8 MFMA, 4 ds_read
    f32x4 st[2][2];   // [kvt][qt]
    __builtin_amdgcn_s_setprio(1);
#pragma unroll
    for (int kvt = 0; kvt < 2; ++kvt) {
      int krow = wk * 32 + kvt * 16 + fr;
      bf16x8 kf0 = ldfrag(Kc + krow * 64 + ((fq * 8)      ^ ((krow & 7) << 3)));
      bf16x8 kf1 = ldfrag(Kc + krow * 64 + ((fq * 8 + 32) ^ ((krow & 7) << 3)));
#pragma unroll
      for (int qt = 0; qt < 2; ++qt) {
        f32x4 z = {};
        z = __builtin_amdgcn_mfma_f32_16x16x32_bf16(kf0, qa[qt][0], z, 0, 0, 0);
        z = __builtin_amdgcn_mfma_f32_16x16x32_bf16(kf1, qa[qt][1], z, 0, 0, 0);
        st[kvt][qt] = z;
      }
    }
    __builtin_amdgcn_s_setprio(0);

    // ---- p = exp2(s); mask on diagonal tile; pack to bf16 pairs
    uint32_t W[2][2][2];   // [qt][kvt][hh]
#pragma unroll
    for (int qt = 0; qt < 2; ++qt) {
      int qrow = q0 + wh * 32 + qt * 16 + fr;
#pragma unroll
      for (int kvt = 0; kvt < 2; ++kvt) {
        float p0, p1, p2, p3;
        if (kb < qb) {
          p0 = exp2f(st[kvt][qt][0]);
          p1 = exp2f(st[kvt][qt][1]);
          p2 = exp2f(st[kvt][qt][2]);
          p3 = exp2f(st[kvt][qt][3]);
        } else {
          int kvg = kb * 64 + wk * 32 + kvt * 16 + fq * 4;
          p0 = (kvg + 0 > qrow) ? 0.f : exp2f(st[kvt][qt][0]);
          p1 = (kvg + 1 > qrow) ? 0.f : exp2f(st[kvt][qt][1]);
          p2 = (kvg + 2 > qrow) ? 0.f : exp2f(st[kvt][qt][2]);
          p3 = (kvg + 3 > qrow) ? 0.f : exp2f(st[kvt][qt][3]);
        }
        ssum[qt] += (p0 + p1) + (p2 + p3);
        W[qt][kvt][0] = cvt_pk_bf16(p0, p1);
        W[qt][kvt][1] = cvt_pk_bf16(p2, p3);
      }
    }

    // ---- permlane P redistribution per qt (r10 pattern): kv-local 0..31
    union U { uint32_t u[4]; bf16x8 v; };
    U pa[2];
#pragma unroll
    for (int qt = 0; qt < 2; ++qt)
#pragma unroll
      for (int hh = 0; hh < 2; ++hh) {
        uint32_t a0 = W[qt][0][hh], b0 = W[qt][1][hh];
        asm("v_permlane32_swap_b32 %0, %1" : "+v"(a0), "+v"(b0));
        asm("v_permlane16_swap_b32 %0, %1" : "+v"(a0), "+v"(b0));
        pa[qt].u[hh] = a0; pa[qt].u[2 + hh] = b0;
      }

    // ---- O += P V over wave's kv-half: 8 MFMA, 4 ds_read
    __builtin_amdgcn_s_setprio(1);
#pragma unroll
    for (int ht = 0; ht < 4; ++ht) {
      int vrow = ht * 16 + fr;
      bf16x8 vb = ldfrag(Vc + vrow * 64 + ((wk * 32 + fq * 8) ^ ((vrow & 7) << 3)));
#pragma unroll
      for (int qt = 0; qt < 2; ++qt)
        accO[qt][ht] = __builtin_amdgcn_mfma_f32_16x16x32_bf16(pa[qt].v, vb, accO[qt][ht], 0, 0, 0);
    }
    __builtin_amdgcn_s_setprio(0);
    cur ^= 1;
  }

  // ---- wave-local ssum reduce over fq copies
#pragma unroll
  for (int qt = 0; qt < 2; ++qt) {
    ssum[qt] += __shfl_xor(ssum[qt], 16);
    ssum[qt] += __shfl_xor(ssum[qt], 32);
  }

  // ---- cross-wk reduce via dead Ks/Vs LDS (all tile reads done after barrier)
  __syncthreads();
  float* Ored = (float*)Ks;          // 16 frags x 64 lanes x 4 f32 = 16 KB
  float* Sred = (float*)Vs;          // 128 f32
  if (wk == 1) {
#pragma unroll
    for (int qt = 0; qt < 2; ++qt)
#pragma unroll
      for (int ht = 0; ht < 4; ++ht)
        *reinterpret_cast<f32x4*>(&Ored[(((wh * 2 + qt) * 4 + ht) << 8) + lane * 4]) = accO[qt][ht];
    if (fq == 0) {
      Sred[wh * 64 + fr]      = ssum[0];
      Sred[wh * 64 + 16 + fr] = ssum[1];
    }
  }
  __syncthreads();
  if (wk == 0) {
#pragma unroll
    for (int qt = 0; qt < 2; ++qt)
#pragma unroll
      for (int ht = 0; ht < 4; ++ht) {
        f32x4 o = *reinterpret_cast<const f32x4*>(&Ored[(((wh * 2 + qt) * 4 + ht) << 8) + lane * 4]);
        accO[qt][ht] += o;
      }
    float invq[2][4];
#pragma unroll
    for (int qt = 0; qt < 2; ++qt) {
      float s = ssum[qt] + Sred[wh * 64 + qt * 16 + fr];
      float inv = 1.0f / s;                       // for q = ..+qt*16+fr
#pragma unroll
      for (int r = 0; r < 4; ++r) invq[qt][r] = __shfl(inv, fq * 4 + r);
    }
#pragma unroll
    for (int qt = 0; qt < 2; ++qt)
#pragma unroll
      for (int ht = 0; ht < 4; ++ht)
#pragma unroll
        for (int r = 0; r < 4; ++r) {
          float o = accO[qt][ht][r] * invq[qt][r];
          int qr = q0 + wh * 32 + qt * 16 + fq * 4 + r;
          Ow[((size_t)b * 2048 + qr) * 1024 + h * 64 + ht * 16 + fr] = f2bf(o);
        }
  }
}

// ---------------------------------------------------------------------------
// Output projection: O[4096][1024] x Wo[1024][1024]^T + b -> y fp32
// ---------------------------------------------------------------------------
__global__ __launch_bounds__(256) void proj_gemm_kernel(
    const u16* __restrict__ Ob, const u16* __restrict__ Wob,
    const float* __restrict__ bias, float* __restrict__ out) {
  __shared__ u16 As[128 * 32];
  __shared__ u16 Bs[128 * 32];
  const int NB = 8;
  int m0 = (blockIdx.x / NB) * 128, n0 = (blockIdx.x % NB) * 128;
  f32x4 acc[4][4] = {};
  gemm128_core(Ob, Wob, m0, n0, 1024, As, Bs, acc);

  const int lane = threadIdx.x & 63, wid = threadIdx.x >> 6;
  const int wr = wid >> 1, wc = wid & 1, fq = lane >> 4, fr = lane & 15;
#pragma unroll
  for (int i = 0; i < 4; ++i)
#pragma unroll
    for (int j = 0; j < 4; ++j)
#pragma unroll
      for (int r = 0; r < 4; ++r) {
        int m = m0 + wr * 64 + i * 16 + fq * 4 + r;
        int n = n0 + wc * 64 + j * 16 + fr;
        out[(size_t)m * 1024 + n] = acc[i][j][r] + bias[n];
      }
}

// ---------------------------------------------------------------------------
extern "C" void kernel_launch(void* const* d_in, const int* in_sizes, int n_in,
                              void* d_out, int out_size, void* d_ws, size_t ws_size,
                              hipStream_t stream) {
  const float* x    = (const float*)d_in[0];
  const float* wqkv = (const float*)d_in[1];
  const float* wo   = (const float*)d_in[2];
  const float* wo_b = (const float*)d_in[3];
  float* out = (float*)d_out;

  u16* xb    = (u16*)d_ws;            // 4096*1024
  u16* wqkvb = xb    + 4194304;       // 3072*1024
  u16* wob   = wqkvb + 3145728;       // 1024*1024
  u16* q_ws  = wob   + 1048576;       // [2,16,2048,64] (pre-scaled)
  u16* k_ws  = q_ws  + 4194304;       // [2,16,2048,64]
  u16* vt_ws = k_ws  + 4194304;       // [2,16,64,2048]  (V^T)
  u16* o_ws  = vt_ws + 4194304;       // [4096,1024]

  static bool attr_set = false;
  if (!attr_set) {
    hipFuncSetAttribute((const void*)qkv_gemm_kernel,
                        hipFuncAttributeMaxDynamicSharedMemorySize, 131072);
    attr_set = true;
  }

  cvt_all<<<2048, 256, 0, stream>>>(x, wqkv, wo, xb, wqkvb, wob);
  qkv_gemm_kernel<<<192, 512, 131072, stream>>>(xb, wqkvb, q_ws, k_ws, vt_ws, out);
  attn_kernel<<<32 * 32, 256, 0, stream>>>(q_ws, k_ws, vt_ws, o_ws);
  proj_gemm_kernel<<<32 * 8, 256, 0, stream>>>(o_ws, wob, wo_b, out);
}

// Round 14
// 113.838 us; speedup vs baseline: 1.0862x; 1.0231x over previous
//
#include <hip/hip_runtime.h>
#include <cstdint>
#include <cstddef>

// ---------------------------------------------------------------------------
// MHA forward: x[2,2048,1024] fp32, wqkv[3072,1024], wo[1024,1024], wo_b[1024]
// out = concat(y[2,2048,1024], k[2,16,2048,64], v[2,16,2048,64]) fp32
// Pipeline: cvt->bf16 (fused); QKV GEMM (256x192 tiles -> grid 256 = exactly
// 1 block/CU, 2-phase fine interleave, counted vmcnt(3), Q pre-scaled);
// flash causal attn (r13: kv-half x q-half waves, permlane in-reg P);
// proj GEMM (128x128 m97-structure).
// ---------------------------------------------------------------------------

using bf16x8 = __attribute__((ext_vector_type(8))) __bf16;
using f32x4  = __attribute__((ext_vector_type(4))) float;
using u16    = unsigned short;

#define SOFT_SCALE 0.1803368801111244f   // 0.125 * log2(e)  (attn in exp2 domain)

// fp32 -> bf16 bits, round-to-nearest-even
__device__ __forceinline__ u16 f2bf(float f) {
  union { float f; uint32_t u; } a; a.f = f;
  uint32_t r = a.u + 0x7fffu + ((a.u >> 16) & 1u);
  return (u16)(r >> 16);
}

__device__ __forceinline__ bf16x8 ldfrag(const u16* p) {
  return *reinterpret_cast<const bf16x8*>(p);
}

__device__ __forceinline__ void gload_lds16(const void* g, void* l) {
  __builtin_amdgcn_global_load_lds((const __attribute__((address_space(1))) void*)g,
                                   (__attribute__((address_space(3))) void*)l,
                                   16, 0, 0);
}

// pack two fp32 -> one u32 of two bf16 (lo = a, hi = b), RNE
__device__ __forceinline__ uint32_t cvt_pk_bf16(float a, float b) {
  uint32_t r;
  asm("v_cvt_pk_bf16_f32 %0, %1, %2" : "=v"(r) : "v"(a), "v"(b));
  return r;
}

// ---------------------------------------------------------------------------
// fused fp32 -> bf16 convert for x, wqkv, wo (single launch)
// ---------------------------------------------------------------------------
__global__ void cvt_all(const float* __restrict__ x, const float* __restrict__ wqkv,
                        const float* __restrict__ wo,
                        u16* __restrict__ xb, u16* __restrict__ wqkvb, u16* __restrict__ wob) {
  int i = blockIdx.x * blockDim.x + threadIdx.x;
  int stride = gridDim.x * blockDim.x;
  for (; i < 2097152; i += stride) {
    const float* src; u16* dst; int j;
    if (i < 1048576)      { src = x;    dst = xb;    j = i; }
    else if (i < 1835008) { src = wqkv; dst = wqkvb; j = i - 1048576; }
    else                  { src = wo;   dst = wob;   j = i - 1835008; }
    float4 v = reinterpret_cast<const float4*>(src)[j];
    ushort4 o;
    o.x = f2bf(v.x); o.y = f2bf(v.y); o.z = f2bf(v.z); o.w = f2bf(v.w);
    reinterpret_cast<ushort4*>(dst)[j] = o;
  }
}

// ---------------------------------------------------------------------------
// QKV GEMM: X[4096][1024] x Wqkv[3072][1024]^T, tile 256x192 -> 16x16 = 256
// blocks = exactly 1/CU. 512 thr = 8 waves (2M x 4N), per-wave 128x48 out
// (8m x 3n frags). BK=64, 16 K-tiles. LDS 112KB: A 2x32KB @0, B 2x24KB
// @65536, XOR-swizzled. 2 phases/tile; stage slots: P0 A-h0(t+1), P1
// A-h1(t+1)+B(t+2); boundary vmcnt(3) (B(t+2)'s 3 loads stay in flight).
// ---------------------------------------------------------------------------
__global__ __launch_bounds__(512, 2) void qkv_gemm_kernel(
    const u16* __restrict__ Xb, const u16* __restrict__ Wb,
    u16* __restrict__ Qws, u16* __restrict__ Kws, u16* __restrict__ Vtws,
    float* __restrict__ out) {
  extern __shared__ char smem[];

  const int tid = threadIdx.x, lane = tid & 63, wid = tid >> 6;
  const int wr = wid >> 2, wc = wid & 3;
  const int fq = lane >> 4, fr = lane & 15;

  // bijective chunked XCD swizzle (256 % 8 == 0)
  const int wg = (blockIdx.x & 7) * 32 + (blockIdx.x >> 3);
  const int bm = wg >> 4, bn = wg & 15;
  const int m0 = bm * 256, n0 = bn * 192;

  const char* Ab = (const char*)Xb + (size_t)m0 * 2048;
  const char* Bb = (const char*)Wb + (size_t)n0 * 2048;

  f32x4 acc[8][3] = {};

  // stage A half-tile (128 rows x 64 cols = 16KB): 2 gload_lds per thread
  auto stage_A = [&](int t, int h) {
    char* dst = smem + (t & 1) * 32768 + h * 16384;
#pragma unroll
    for (int l = 0; l < 2; ++l) {
      int lin = (l * 512 + tid) * 16;
      int rl  = lin >> 7;
      int col = (lin & 127) ^ ((rl & 7) << 4);
      gload_lds16(Ab + (size_t)(h * 128 + rl) * 2048 + t * 128 + col, dst + lin);
    }
  };
  // stage B tile (192 rows x 64 cols = 24KB): 3 gload_lds per thread
  auto stage_B = [&](int t) {
    char* dst = smem + 65536 + (t & 1) * 24576;
#pragma unroll
    for (int l = 0; l < 3; ++l) {
      int lin = (l * 512 + tid) * 16;
      int rl  = lin >> 7;
      int col = (lin & 127) ^ ((rl & 7) << 4);
      gload_lds16(Bb + (size_t)rl * 2048 + t * 128 + col, dst + lin);
    }
  };

  // prologue: A(0) [4], B(0) [3], B(1) [3] -> wait until only B(1)'s 3 left
  stage_A(0, 0); stage_A(0, 1);
  stage_B(0);
  stage_B(1);
  asm volatile("s_waitcnt vmcnt(3)" ::: "memory");
  __builtin_amdgcn_s_barrier();

  bf16x8 afr[4][2];   // current m-set (4 m x 2 ks)
  bf16x8 bfr[3][2];   // 3 n x 2 ks

  for (int t = 0; t < 16; ++t) {
    const char* As = smem + (t & 1) * 32768;
    const char* Bs = smem + 65536 + (t & 1) * 24576;

    // ---------- P0: read A m0-3 + B all; stage A-h0(t+1); MFMA m0-3 x n0-2
#pragma unroll
    for (int m = 0; m < 4; ++m) {
      int row = wr * 128 + m * 16 + fr;
#pragma unroll
      for (int ks = 0; ks < 2; ++ks)
        afr[m][ks] = *(const bf16x8*)(As + row * 128 + ((ks * 64 + fq * 16) ^ ((row & 7) << 4)));
    }
#pragma unroll
    for (int n = 0; n < 3; ++n) {
      int row = wc * 48 + n * 16 + fr;
#pragma unroll
      for (int ks = 0; ks < 2; ++ks)
        bfr[n][ks] = *(const bf16x8*)(Bs + row * 128 + ((ks * 64 + fq * 16) ^ ((row & 7) << 4)));
    }
    if (t + 1 < 16) stage_A(t + 1, 0);
    __builtin_amdgcn_s_barrier();
    asm volatile("s_waitcnt lgkmcnt(0)" ::: "memory");
    __builtin_amdgcn_sched_barrier(0);
    __builtin_amdgcn_s_setprio(1);
#pragma unroll
    for (int m = 0; m < 4; ++m)
#pragma unroll
      for (int n = 0; n < 3; ++n)
#pragma unroll
        for (int ks = 0; ks < 2; ++ks)
          acc[m][n] = __builtin_amdgcn_mfma_f32_16x16x32_bf16(afr[m][ks], bfr[n][ks], acc[m][n], 0, 0, 0);
    __builtin_amdgcn_s_setprio(0);
    __builtin_amdgcn_s_barrier();

    // ---------- P1: read A m4-7; stage A-h1(t+1) + B(t+2); MFMA m4-7 x n0-2
#pragma unroll
    for (int m = 0; m < 4; ++m) {
      int row = wr * 128 + (m + 4) * 16 + fr;
#pragma unroll
      for (int ks = 0; ks < 2; ++ks)
        afr[m][ks] = *(const bf16x8*)(As + row * 128 + ((ks * 64 + fq * 16) ^ ((row & 7) << 4)));
    }
    if (t + 1 < 16) stage_A(t + 1, 1);
    if (t + 2 < 16) stage_B(t + 2);
    __builtin_amdgcn_s_barrier();
    asm volatile("s_waitcnt lgkmcnt(0)" ::: "memory");
    __builtin_amdgcn_sched_barrier(0);
    __builtin_amdgcn_s_setprio(1);
#pragma unroll
    for (int m = 0; m < 4; ++m)
#pragma unroll
      for (int n = 0; n < 3; ++n)
#pragma unroll
        for (int ks = 0; ks < 2; ++ks)
          acc[m + 4][n] = __builtin_amdgcn_mfma_f32_16x16x32_bf16(afr[m][ks], bfr[n][ks], acc[m + 4][n], 0, 0, 0);
    __builtin_amdgcn_s_setprio(0);
    // tile boundary: A(t+1) must land; allow B(t+2)'s 3 loads in flight
    if (t < 14)       asm volatile("s_waitcnt vmcnt(3)" ::: "memory");
    else if (t == 14) asm volatile("s_waitcnt vmcnt(0)" ::: "memory");
    __builtin_amdgcn_s_barrier();
  }

  // ---- epilogue: sect per n-frag (frag-uniform: 1024 % 16 == 0)
  const int mbase = m0 + wr * 128;
#pragma unroll
  for (int m = 0; m < 8; ++m)
#pragma unroll
    for (int n = 0; n < 3; ++n) {
      int mB = mbase + m * 16 + fq * 4;
      int ncol = n0 + wc * 48 + n * 16 + fr;
      int sect = ncol >> 10;
      int nn = ncol & 1023;
      int b = mB >> 11, s0 = mB & 2047;
      int h = nn >> 6, hd = nn & 63;
      size_t base = (((size_t)b * 16 + h) * 2048 + s0) * 64 + hd;
      float v0 = acc[m][n][0], v1 = acc[m][n][1], v2 = acc[m][n][2], v3 = acc[m][n][3];
      if (sect == 0) {
        Qws[base]       = f2bf(v0 * SOFT_SCALE);
        Qws[base + 64]  = f2bf(v1 * SOFT_SCALE);
        Qws[base + 128] = f2bf(v2 * SOFT_SCALE);
        Qws[base + 192] = f2bf(v3 * SOFT_SCALE);
      } else if (sect == 1) {
        Kws[base] = f2bf(v0); Kws[base + 64] = f2bf(v1);
        Kws[base + 128] = f2bf(v2); Kws[base + 192] = f2bf(v3);
        out[4194304 + base] = v0; out[4194304 + base + 64] = v1;
        out[4194304 + base + 128] = v2; out[4194304 + base + 192] = v3;
      } else {
        out[8388608 + base] = v0; out[8388608 + base + 64] = v1;
        out[8388608 + base + 128] = v2; out[8388608 + base + 192] = v3;
        size_t tt = ((size_t)(b * 16 + h) * 64 + hd) * 2048 + s0;
        ushort4 pk; pk.x = f2bf(v0); pk.y = f2bf(v1); pk.z = f2bf(v2); pk.w = f2bf(v3);
        *reinterpret_cast<ushort4*>(Vtws + tt) = pk;
      }
    }
}

// ---------------------------------------------------------------------------
// 128x128 tile GEMM core (m97 structure) — used by proj only.
// ---------------------------------------------------------------------------
__device__ __forceinline__ void gemm128_core(const u16* __restrict__ A,
                                             const u16* __restrict__ B,
                                             int m0, int n0, int K,
                                             u16* As, u16* Bs, f32x4 acc[4][4]) {
  const int tid  = threadIdx.x;
  const int lane = tid & 63;
  const int wid  = tid >> 6;
  const int wr = wid >> 1, wc = wid & 1;
  const int fq = lane >> 4, fr = lane & 15;

  for (int kb = 0; kb < K; kb += 32) {
#pragma unroll
    for (int j = 0; j < 2; ++j) {
      int lin = (j * 256 + tid) * 16;
      int row = lin >> 6;
      int rb  = lin & 63;
      gload_lds16((const char*)(A + (size_t)(m0 + row) * K + kb) + rb, (char*)As + lin);
      gload_lds16((const char*)(B + (size_t)(n0 + row) * K + kb) + rb, (char*)Bs + lin);
    }
    __syncthreads();

    bf16x8 av[4], bv[4];
#pragma unroll
    for (int i = 0; i < 4; ++i) av[i] = ldfrag(As + (wr * 64 + i * 16 + fr) * 32 + fq * 8);
#pragma unroll
    for (int j = 0; j < 4; ++j) bv[j] = ldfrag(Bs + (wc * 64 + j * 16 + fr) * 32 + fq * 8);
    __builtin_amdgcn_s_setprio(1);
#pragma unroll
    for (int i = 0; i < 4; ++i)
#pragma unroll
      for (int j = 0; j < 4; ++j)
        acc[i][j] = __builtin_amdgcn_mfma_f32_16x16x32_bf16(av[i], bv[j], acc[i][j], 0, 0, 0);
    __builtin_amdgcn_s_setprio(0);
    __syncthreads();
  }
}

// ---------------------------------------------------------------------------
// Flash causal attention (r13). grid = 1024; block = 256 (4 waves).
// Wave (wk,wh) owns kv-half wk x q-half wh. Swapped QK^T, permlane in-reg P,
// no-max softmax (Q pre-scaled), end-only cross-wk reduce via dead LDS.
// ---------------------------------------------------------------------------
__global__ __launch_bounds__(256, 4) void attn_kernel(
    const u16* __restrict__ Qw, const u16* __restrict__ Kw,
    const u16* __restrict__ Vtw, u16* __restrict__ Ow) {
  __shared__ u16 Ks[2][64 * 64];
  __shared__ u16 Vs[2][64 * 64];

  const int tid = threadIdx.x, lane = tid & 63, wid = tid >> 6;
  const int wk = wid >> 1, wh = wid & 1;
  const int fq = lane >> 4, fr = lane & 15;
  const int bh = blockIdx.x & 31;
  const int qb = 31 - (blockIdx.x >> 5);   // heavy blocks first
  const int b = bh >> 4, h = bh & 15;
  const int q0 = qb * 64;

  const u16* Qbase  = Qw  + (size_t)bh * 2048 * 64;
  const u16* Kbase  = Kw  + (size_t)bh * 2048 * 64;
  const char* VtBase = (const char*)(Vtw + (size_t)bh * 64 * 2048);

#pragma unroll
  for (int f = 0; f < 2; ++f) {
    int lin = (f * 256 + tid) * 16;
    int row = lin >> 7;
    int logical = lin ^ ((row & 7) << 4);
    gload_lds16((const char*)Kbase + logical, (char*)Ks[0] + lin);
    gload_lds16(VtBase + (size_t)row * 4096 + (logical & 127), (char*)Vs[0] + lin);
  }

  bf16x8 qa[2][2];   // [qt][kh]
#pragma unroll
  for (int qt = 0; qt < 2; ++qt)
#pragma unroll
    for (int kh = 0; kh < 2; ++kh)
      qa[qt][kh] = ldfrag(Qbase + (size_t)(q0 + wh * 32 + qt * 16 + fr) * 64 + kh * 32 + fq * 8);

  float ssum[2] = {0.f, 0.f};
  f32x4 accO[2][4] = {};

  int cur = 0;
  for (int kb = 0; kb <= qb; ++kb) {
    __syncthreads();

    if (kb < qb) {
      const char* kg = (const char*)(Kbase + (size_t)(kb + 1) * 64 * 64);
#pragma unroll
      for (int f = 0; f < 2; ++f) {
        int lin = (f * 256 + tid) * 16;
        int row = lin >> 7;
        int logical = lin ^ ((row & 7) << 4);
        gload_lds16(kg + logical, (char*)Ks[cur ^ 1] + lin);
        gload_lds16(VtBase + (size_t)row * 4096 + (size_t)(kb + 1) * 128 + (logical & 127),
                    (char*)Vs[cur ^ 1] + lin);
      }
    }

    const u16* Kc = Ks[cur];
    const u16* Vc = Vs[cur];

    f32x4 st[2][2];   // [kvt][qt]
    __builtin_amdgcn_s_setprio(1);
#pragma unroll
    for (int kvt = 0; kvt < 2; ++kvt) {
      int krow = wk * 32 + kvt * 16 + fr;
      bf16x8 kf0 = ldfrag(Kc + krow * 64 + ((fq * 8)      ^ ((krow & 7) << 3)));
      bf16x8 kf1 = ldfrag(Kc + krow * 64 + ((fq * 8 + 32) ^ ((krow & 7) << 3)));
#pragma unroll
      for (int qt = 0; qt < 2; ++qt) {
        f32x4 z = {};
        z = __builtin_amdgcn_mfma_f32_16x16x32_bf16(kf0, qa[qt][0], z, 0, 0, 0);
        z = __builtin_amdgcn_mfma_f32_16x16x32_bf16(kf1, qa[qt][1], z, 0, 0, 0);
        st[kvt][qt] = z;
      }
    }
    __builtin_amdgcn_s_setprio(0);

    uint32_t W[2][2][2];   // [qt][kvt][hh]
#pragma unroll
    for (int qt = 0; qt < 2; ++qt) {
      int qrow = q0 + wh * 32 + qt * 16 + fr;
#pragma unroll
      for (int kvt = 0; kvt < 2; ++kvt) {
        float p0, p1, p2, p3;
        if (kb < qb) {
          p0 = exp2f(st[kvt][qt][0]);
          p1 = exp2f(st[kvt][qt][1]);
          p2 = exp2f(st[kvt][qt][2]);
          p3 = exp2f(st[kvt][qt][3]);
        } else {
          int kvg = kb * 64 + wk * 32 + kvt * 16 + fq * 4;
          p0 = (kvg + 0 > qrow) ? 0.f : exp2f(st[kvt][qt][0]);
          p1 = (kvg + 1 > qrow) ? 0.f : exp2f(st[kvt][qt][1]);
          p2 = (kvg + 2 > qrow) ? 0.f : exp2f(st[kvt][qt][2]);
          p3 = (kvg + 3 > qrow) ? 0.f : exp2f(st[kvt][qt][3]);
        }
        ssum[qt] += (p0 + p1) + (p2 + p3);
        W[qt][kvt][0] = cvt_pk_bf16(p0, p1);
        W[qt][kvt][1] = cvt_pk_bf16(p2, p3);
      }
    }

    union U { uint32_t u[4]; bf16x8 v; };
    U pa[2];
#pragma unroll
    for (int qt = 0; qt < 2; ++qt)
#pragma unroll
      for (int hh = 0; hh < 2; ++hh) {
        uint32_t a0 = W[qt][0][hh], b0 = W[qt][1][hh];
        asm("v_permlane32_swap_b32 %0, %1" : "+v"(a0), "+v"(b0));
        asm("v_permlane16_swap_b32 %0, %1" : "+v"(a0), "+v"(b0));
        pa[qt].u[hh] = a0; pa[qt].u[2 + hh] = b0;
      }

    __builtin_amdgcn_s_setprio(1);
#pragma unroll
    for (int ht = 0; ht < 4; ++ht) {
      int vrow = ht * 16 + fr;
      bf16x8 vb = ldfrag(Vc + vrow * 64 + ((wk * 32 + fq * 8) ^ ((vrow & 7) << 3)));
#pragma unroll
      for (int qt = 0; qt < 2; ++qt)
        accO[qt][ht] = __builtin_amdgcn_mfma_f32_16x16x32_bf16(pa[qt].v, vb, accO[qt][ht], 0, 0, 0);
    }
    __builtin_amdgcn_s_setprio(0);
    cur ^= 1;
  }

#pragma unroll
  for (int qt = 0; qt < 2; ++qt) {
    ssum[qt] += __shfl_xor(ssum[qt], 16);
    ssum[qt] += __shfl_xor(ssum[qt], 32);
  }

  __syncthreads();
  float* Ored = (float*)Ks;
  float* Sred = (float*)Vs;
  if (wk == 1) {
#pragma unroll
    for (int qt = 0; qt < 2; ++qt)
#pragma unroll
      for (int ht = 0; ht < 4; ++ht)
        *reinterpret_cast<f32x4*>(&Ored[(((wh * 2 + qt) * 4 + ht) << 8) + lane * 4]) = accO[qt][ht];
    if (fq == 0) {
      Sred[wh * 64 + fr]      = ssum[0];
      Sred[wh * 64 + 16 + fr] = ssum[1];
    }
  }
  __syncthreads();
  if (wk == 0) {
#pragma unroll
    for (int qt = 0; qt < 2; ++qt)
#pragma unroll
      for (int ht = 0; ht < 4; ++ht) {
        f32x4 o = *reinterpret_cast<const f32x4*>(&Ored[(((wh * 2 + qt) * 4 + ht) << 8) + lane * 4]);
        accO[qt][ht] += o;
      }
    float invq[2][4];
#pragma unroll
    for (int qt = 0; qt < 2; ++qt) {
      float s = ssum[qt] + Sred[wh * 64 + qt * 16 + fr];
      float inv = 1.0f / s;
#pragma unroll
      for (int r = 0; r < 4; ++r) invq[qt][r] = __shfl(inv, fq * 4 + r);
    }
#pragma unroll
    for (int qt = 0; qt < 2; ++qt)
#pragma unroll
      for (int ht = 0; ht < 4; ++ht)
#pragma unroll
        for (int r = 0; r < 4; ++r) {
          float o = accO[qt][ht][r] * invq[qt][r];
          int qr = q0 + wh * 32 + qt * 16 + fq * 4 + r;
          Ow[((size_t)b * 2048 + qr) * 1024 + h * 64 + ht * 16 + fr] = f2bf(o);
        }
  }
}

// ---------------------------------------------------------------------------
// Output projection: O[4096][1024] x Wo[1024][1024]^T + b -> y fp32
// ---------------------------------------------------------------------------
__global__ __launch_bounds__(256) void proj_gemm_kernel(
    const u16* __restrict__ Ob, const u16* __restrict__ Wob,
    const float* __restrict__ bias, float* __restrict__ out) {
  __shared__ u16 As[128 * 32];
  __shared__ u16 Bs[128 * 32];
  const int NB = 8;
  int m0 = (blockIdx.x / NB) * 128, n0 = (blockIdx.x % NB) * 128;
  f32x4 acc[4][4] = {};
  gemm128_core(Ob, Wob, m0, n0, 1024, As, Bs, acc);

  const int lane = threadIdx.x & 63, wid = threadIdx.x >> 6;
  const int wr = wid >> 1, wc = wid & 1, fq = lane >> 4, fr = lane & 15;
#pragma unroll
  for (int i = 0; i < 4; ++i)
#pragma unroll
    for (int j = 0; j < 4; ++j)
#pragma unroll
      for (int r = 0; r < 4; ++r) {
        int m = m0 + wr * 64 + i * 16 + fq * 4 + r;
        int n = n0 + wc * 64 + j * 16 + fr;
        out[(size_t)m * 1024 + n] = acc[i][j][r] + bias[n];
      }
}

// ---------------------------------------------------------------------------
extern "C" void kernel_launch(void* const* d_in, const int* in_sizes, int n_in,
                              void* d_out, int out_size, void* d_ws, size_t ws_size,
                              hipStream_t stream) {
  const float* x    = (const float*)d_in[0];
  const float* wqkv = (const float*)d_in[1];
  const float* wo   = (const float*)d_in[2];
  const float* wo_b = (const float*)d_in[3];
  float* out = (float*)d_out;

  u16* xb    = (u16*)d_ws;            // 4096*1024
  u16* wqkvb = xb    + 4194304;       // 3072*1024
  u16* wob   = wqkvb + 3145728;       // 1024*1024
  u16* q_ws  = wob   + 1048576;       // [2,16,2048,64] (pre-scaled)
  u16* k_ws  = q_ws  + 4194304;       // [2,16,2048,64]
  u16* vt_ws = k_ws  + 4194304;       // [2,16,64,2048]  (V^T)
  u16* o_ws  = vt_ws + 4194304;       // [4096,1024]

  static bool attr_set = false;
  if (!attr_set) {
    hipFuncSetAttribute((const void*)qkv_gemm_kernel,
                        hipFuncAttributeMaxDynamicSharedMemorySize, 131072);
    attr_set = true;
  }

  cvt_all<<<2048, 256, 0, stream>>>(x, wqkv, wo, xb, wqkvb, wob);
  qkv_gemm_kernel<<<256, 512, 114688, stream>>>(xb, wqkvb, q_ws, k_ws, vt_ws, out);
  attn_kernel<<<32 * 32, 256, 0, stream>>>(q_ws, k_ws, vt_ws, o_ws);
  proj_gemm_kernel<<<32 * 8, 256, 0, stream>>>(o_ws, wob, wo_b, out);
}

// Round 18
// 112.579 us; speedup vs baseline: 1.0984x; 1.0112x over previous
//
#include <hip/hip_runtime.h>
#include <cstdint>
#include <cstddef>

// ---------------------------------------------------------------------------
// MHA forward: x[2,2048,1024] fp32, wqkv[3072,1024], wo[1024,1024], wo_b[1024]
// out = concat(y[2,2048,1024], k[2,16,2048,64], v[2,16,2048,64]) fp32
// Pipeline: cvt->bf16 (fused); QKV GEMM (128x192 tiles -> grid 512 = 2
// blocks/CU, 80KB LDS, 2-phase fine interleave, counted vmcnt(3), Q
// pre-scaled); flash causal attn (r13: kv-half x q-half waves, permlane
// in-reg P); proj GEMM (128x128 m97-structure).
// ---------------------------------------------------------------------------

using bf16x8 = __attribute__((ext_vector_type(8))) __bf16;
using f32x4  = __attribute__((ext_vector_type(4))) float;
using u16    = unsigned short;

#define SOFT_SCALE 0.1803368801111244f   // 0.125 * log2(e)  (attn in exp2 domain)

// fp32 -> bf16 bits, round-to-nearest-even
__device__ __forceinline__ u16 f2bf(float f) {
  union { float f; uint32_t u; } a; a.f = f;
  uint32_t r = a.u + 0x7fffu + ((a.u >> 16) & 1u);
  return (u16)(r >> 16);
}

__device__ __forceinline__ bf16x8 ldfrag(const u16* p) {
  return *reinterpret_cast<const bf16x8*>(p);
}

__device__ __forceinline__ void gload_lds16(const void* g, void* l) {
  __builtin_amdgcn_global_load_lds((const __attribute__((address_space(1))) void*)g,
                                   (__attribute__((address_space(3))) void*)l,
                                   16, 0, 0);
}

// pack two fp32 -> one u32 of two bf16 (lo = a, hi = b), RNE
__device__ __forceinline__ uint32_t cvt_pk_bf16(float a, float b) {
  uint32_t r;
  asm("v_cvt_pk_bf16_f32 %0, %1, %2" : "=v"(r) : "v"(a), "v"(b));
  return r;
}

// ---------------------------------------------------------------------------
// fused fp32 -> bf16 convert for x, wqkv, wo (single launch)
// ---------------------------------------------------------------------------
__global__ void cvt_all(const float* __restrict__ x, const float* __restrict__ wqkv,
                        const float* __restrict__ wo,
                        u16* __restrict__ xb, u16* __restrict__ wqkvb, u16* __restrict__ wob) {
  int i = blockIdx.x * blockDim.x + threadIdx.x;
  int stride = gridDim.x * blockDim.x;
  for (; i < 2097152; i += stride) {
    const float* src; u16* dst; int j;
    if (i < 1048576)      { src = x;    dst = xb;    j = i; }
    else if (i < 1835008) { src = wqkv; dst = wqkvb; j = i - 1048576; }
    else                  { src = wo;   dst = wob;   j = i - 1835008; }
    float4 v = reinterpret_cast<const float4*>(src)[j];
    ushort4 o;
    o.x = f2bf(v.x); o.y = f2bf(v.y); o.z = f2bf(v.z); o.w = f2bf(v.w);
    reinterpret_cast<ushort4*>(dst)[j] = o;
  }
}

// ---------------------------------------------------------------------------
// QKV GEMM: X[4096][1024] x Wqkv[3072][1024]^T, tile 128x192 -> 32x16 = 512
// blocks = 2/CU (80KB LDS). 512 thr = 8 waves (2M x 4N), per-wave 64x48
// (4m x 3n frags). BK=64, 16 K-tiles. LDS: A 2x16KB @0, B 2x24KB @32768,
// XOR-swizzled. 2 phases/tile; stage slots: P0 A-h0(t+1), P1 A-h1(t+1) +
// B(t+2); boundary vmcnt(3) (B(t+2)'s 3 loads stay in flight).
// ---------------------------------------------------------------------------
__global__ __launch_bounds__(512, 2) void qkv_gemm_kernel(
    const u16* __restrict__ Xb, const u16* __restrict__ Wb,
    u16* __restrict__ Qws, u16* __restrict__ Kws, u16* __restrict__ Vtws,
    float* __restrict__ out) {
  extern __shared__ char smem[];

  const int tid = threadIdx.x, lane = tid & 63, wid = tid >> 6;
  const int wr = wid >> 2, wc = wid & 3;
  const int fq = lane >> 4, fr = lane & 15;

  // bijective chunked XCD swizzle (512 % 8 == 0)
  const int wg = (blockIdx.x & 7) * 64 + (blockIdx.x >> 3);
  const int bm = wg >> 4, bn = wg & 15;
  const int m0 = bm * 128, n0 = bn * 192;

  const char* Ab = (const char*)Xb + (size_t)m0 * 2048;
  const char* Bb = (const char*)Wb + (size_t)n0 * 2048;

  f32x4 acc[4][3] = {};

  // stage A half-tile (64 rows x 64 cols = 8KB): 1 gload_lds per thread
  auto stage_A = [&](int t, int h) {
    char* dst = smem + (t & 1) * 16384 + h * 8192;
    int lin = tid * 16;
    int rl  = lin >> 7;
    int col = (lin & 127) ^ ((rl & 7) << 4);
    gload_lds16(Ab + (size_t)(h * 64 + rl) * 2048 + t * 128 + col, dst + lin);
  };
  // stage B tile (192 rows x 64 cols = 24KB): 3 gload_lds per thread
  auto stage_B = [&](int t) {
    char* dst = smem + 32768 + (t & 1) * 24576;
#pragma unroll
    for (int l = 0; l < 3; ++l) {
      int lin = (l * 512 + tid) * 16;
      int rl  = lin >> 7;
      int col = (lin & 127) ^ ((rl & 7) << 4);
      gload_lds16(Bb + (size_t)rl * 2048 + t * 128 + col, dst + lin);
    }
  };

  // prologue: A(0) [2], B(0) [3], B(1) [3] -> wait until only B(1)'s 3 left
  stage_A(0, 0); stage_A(0, 1);
  stage_B(0);
  stage_B(1);
  asm volatile("s_waitcnt vmcnt(3)" ::: "memory");
  __builtin_amdgcn_s_barrier();

  bf16x8 afr[2][2];   // current m-pair (2 m x 2 ks)
  bf16x8 bfr[3][2];   // 3 n x 2 ks

  for (int t = 0; t < 16; ++t) {
    const char* As = smem + (t & 1) * 16384;
    const char* Bs = smem + 32768 + (t & 1) * 24576;

    // ---------- P0: read A m0-1 + B all; stage A-h0(t+1); MFMA m0-1 x n0-2
#pragma unroll
    for (int m = 0; m < 2; ++m) {
      int row = wr * 64 + m * 16 + fr;
#pragma unroll
      for (int ks = 0; ks < 2; ++ks)
        afr[m][ks] = *(const bf16x8*)(As + row * 128 + ((ks * 64 + fq * 16) ^ ((row & 7) << 4)));
    }
#pragma unroll
    for (int n = 0; n < 3; ++n) {
      int row = wc * 48 + n * 16 + fr;
#pragma unroll
      for (int ks = 0; ks < 2; ++ks)
        bfr[n][ks] = *(const bf16x8*)(Bs + row * 128 + ((ks * 64 + fq * 16) ^ ((row & 7) << 4)));
    }
    if (t + 1 < 16) stage_A(t + 1, 0);
    __builtin_amdgcn_s_barrier();
    asm volatile("s_waitcnt lgkmcnt(0)" ::: "memory");
    __builtin_amdgcn_sched_barrier(0);
    __builtin_amdgcn_s_setprio(1);
#pragma unroll
    for (int m = 0; m < 2; ++m)
#pragma unroll
      for (int n = 0; n < 3; ++n)
#pragma unroll
        for (int ks = 0; ks < 2; ++ks)
          acc[m][n] = __builtin_amdgcn_mfma_f32_16x16x32_bf16(afr[m][ks], bfr[n][ks], acc[m][n], 0, 0, 0);
    __builtin_amdgcn_s_setprio(0);
    __builtin_amdgcn_s_barrier();

    // ---------- P1: read A m2-3; stage A-h1(t+1) + B(t+2); MFMA m2-3 x n0-2
#pragma unroll
    for (int m = 0; m < 2; ++m) {
      int row = wr * 64 + (m + 2) * 16 + fr;
#pragma unroll
      for (int ks = 0; ks < 2; ++ks)
        afr[m][ks] = *(const bf16x8*)(As + row * 128 + ((ks * 64 + fq * 16) ^ ((row & 7) << 4)));
    }
    if (t + 1 < 16) stage_A(t + 1, 1);
    if (t + 2 < 16) stage_B(t + 2);
    __builtin_amdgcn_s_barrier();
    asm volatile("s_waitcnt lgkmcnt(0)" ::: "memory");
    __builtin_amdgcn_sched_barrier(0);
    __builtin_amdgcn_s_setprio(1);
#pragma unroll
    for (int m = 0; m < 2; ++m)
#pragma unroll
      for (int n = 0; n < 3; ++n)
#pragma unroll
        for (int ks = 0; ks < 2; ++ks)
          acc[m + 2][n] = __builtin_amdgcn_mfma_f32_16x16x32_bf16(afr[m][ks], bfr[n][ks], acc[m + 2][n], 0, 0, 0);
    __builtin_amdgcn_s_setprio(0);
    // tile boundary: A(t+1) must land; allow B(t+2)'s 3 loads in flight
    if (t < 14)       asm volatile("s_waitcnt vmcnt(3)" ::: "memory");
    else if (t == 14) asm volatile("s_waitcnt vmcnt(0)" ::: "memory");
    __builtin_amdgcn_s_barrier();
  }

  // ---- epilogue: sect per n-frag (frag-uniform: 1024 % 16 == 0)
  const int mbase = m0 + wr * 64;
#pragma unroll
  for (int m = 0; m < 4; ++m)
#pragma unroll
    for (int n = 0; n < 3; ++n) {
      int mB = mbase + m * 16 + fq * 4;
      int ncol = n0 + wc * 48 + n * 16 + fr;
      int sect = ncol >> 10;
      int nn = ncol & 1023;
      int b = mB >> 11, s0 = mB & 2047;
      int h = nn >> 6, hd = nn & 63;
      size_t base = (((size_t)b * 16 + h) * 2048 + s0) * 64 + hd;
      float v0 = acc[m][n][0], v1 = acc[m][n][1], v2 = acc[m][n][2], v3 = acc[m][n][3];
      if (sect == 0) {
        Qws[base]       = f2bf(v0 * SOFT_SCALE);
        Qws[base + 64]  = f2bf(v1 * SOFT_SCALE);
        Qws[base + 128] = f2bf(v2 * SOFT_SCALE);
        Qws[base + 192] = f2bf(v3 * SOFT_SCALE);
      } else if (sect == 1) {
        Kws[base] = f2bf(v0); Kws[base + 64] = f2bf(v1);
        Kws[base + 128] = f2bf(v2); Kws[base + 192] = f2bf(v3);
        out[4194304 + base] = v0; out[4194304 + base + 64] = v1;
        out[4194304 + base + 128] = v2; out[4194304 + base + 192] = v3;
      } else {
        out[8388608 + base] = v0; out[8388608 + base + 64] = v1;
        out[8388608 + base + 128] = v2; out[8388608 + base + 192] = v3;
        size_t tt = ((size_t)(b * 16 + h) * 64 + hd) * 2048 + s0;
        ushort4 pk; pk.x = f2bf(v0); pk.y = f2bf(v1); pk.z = f2bf(v2); pk.w = f2bf(v3);
        *reinterpret_cast<ushort4*>(Vtws + tt) = pk;
      }
    }
}

// ---------------------------------------------------------------------------
// 128x128 tile GEMM core (m97 structure) — used by proj only.
// ---------------------------------------------------------------------------
__device__ __forceinline__ void gemm128_core(const u16* __restrict__ A,
                                             const u16* __restrict__ B,
                                             int m0, int n0, int K,
                                             u16* As, u16* Bs, f32x4 acc[4][4]) {
  const int tid  = threadIdx.x;
  const int lane = tid & 63;
  const int wid  = tid >> 6;
  const int wr = wid >> 1, wc = wid & 1;
  const int fq = lane >> 4, fr = lane & 15;

  for (int kb = 0; kb < K; kb += 32) {
#pragma unroll
    for (int j = 0; j < 2; ++j) {
      int lin = (j * 256 + tid) * 16;
      int row = lin >> 6;
      int rb  = lin & 63;
      gload_lds16((const char*)(A + (size_t)(m0 + row) * K + kb) + rb, (char*)As + lin);
      gload_lds16((const char*)(B + (size_t)(n0 + row) * K + kb) + rb, (char*)Bs + lin);
    }
    __syncthreads();

    bf16x8 av[4], bv[4];
#pragma unroll
    for (int i = 0; i < 4; ++i) av[i] = ldfrag(As + (wr * 64 + i * 16 + fr) * 32 + fq * 8);
#pragma unroll
    for (int j = 0; j < 4; ++j) bv[j] = ldfrag(Bs + (wc * 64 + j * 16 + fr) * 32 + fq * 8);
    __builtin_amdgcn_s_setprio(1);
#pragma unroll
    for (int i = 0; i < 4; ++i)
#pragma unroll
      for (int j = 0; j < 4; ++j)
        acc[i][j] = __builtin_amdgcn_mfma_f32_16x16x32_bf16(av[i], bv[j], acc[i][j], 0, 0, 0);
    __builtin_amdgcn_s_setprio(0);
    __syncthreads();
  }
}

// ---------------------------------------------------------------------------
// Flash causal attention (r13). grid = 1024; block = 256 (4 waves).
// Wave (wk,wh) owns kv-half wk x q-half wh. Swapped QK^T, permlane in-reg P,
// no-max softmax (Q pre-scaled), end-only cross-wk reduce via dead LDS.
// ---------------------------------------------------------------------------
__global__ __launch_bounds__(256, 4) void attn_kernel(
    const u16* __restrict__ Qw, const u16* __restrict__ Kw,
    const u16* __restrict__ Vtw, u16* __restrict__ Ow) {
  __shared__ u16 Ks[2][64 * 64];
  __shared__ u16 Vs[2][64 * 64];

  const int tid = threadIdx.x, lane = tid & 63, wid = tid >> 6;
  const int wk = wid >> 1, wh = wid & 1;
  const int fq = lane >> 4, fr = lane & 15;
  const int bh = blockIdx.x & 31;
  const int qb = 31 - (blockIdx.x >> 5);   // heavy blocks first
  const int b = bh >> 4, h = bh & 15;
  const int q0 = qb * 64;

  const u16* Qbase  = Qw  + (size_t)bh * 2048 * 64;
  const u16* Kbase  = Kw  + (size_t)bh * 2048 * 64;
  const char* VtBase = (const char*)(Vtw + (size_t)bh * 64 * 2048);

#pragma unroll
  for (int f = 0; f < 2; ++f) {
    int lin = (f * 256 + tid) * 16;
    int row = lin >> 7;
    int logical = lin ^ ((row & 7) << 4);
    gload_lds16((const char*)Kbase + logical, (char*)Ks[0] + lin);
    gload_lds16(VtBase + (size_t)row * 4096 + (logical & 127), (char*)Vs[0] + lin);
  }

  bf16x8 qa[2][2];   // [qt][kh]
#pragma unroll
  for (int qt = 0; qt < 2; ++qt)
#pragma unroll
    for (int kh = 0; kh < 2; ++kh)
      qa[qt][kh] = ldfrag(Qbase + (size_t)(q0 + wh * 32 + qt * 16 + fr) * 64 + kh * 32 + fq * 8);

  float ssum[2] = {0.f, 0.f};
  f32x4 accO[2][4] = {};

  int cur = 0;
  for (int kb = 0; kb <= qb; ++kb) {
    __syncthreads();

    if (kb < qb) {
      const char* kg = (const char*)(Kbase + (size_t)(kb + 1) * 64 * 64);
#pragma unroll
      for (int f = 0; f < 2; ++f) {
        int lin = (f * 256 + tid) * 16;
        int row = lin >> 7;
        int logical = lin ^ ((row & 7) << 4);
        gload_lds16(kg + logical, (char*)Ks[cur ^ 1] + lin);
        gload_lds16(VtBase + (size_t)row * 4096 + (size_t)(kb + 1) * 128 + (logical & 127),
                    (char*)Vs[cur ^ 1] + lin);
      }
    }

    const u16* Kc = Ks[cur];
    const u16* Vc = Vs[cur];

    f32x4 st[2][2];   // [kvt][qt]
    __builtin_amdgcn_s_setprio(1);
#pragma unroll
    for (int kvt = 0; kvt < 2; ++kvt) {
      int krow = wk * 32 + kvt * 16 + fr;
      bf16x8 kf0 = ldfrag(Kc + krow * 64 + ((fq * 8)      ^ ((krow & 7) << 3)));
      bf16x8 kf1 = ldfrag(Kc + krow * 64 + ((fq * 8 + 32) ^ ((krow & 7) << 3)));
#pragma unroll
      for (int qt = 0; qt < 2; ++qt) {
        f32x4 z = {};
        z = __builtin_amdgcn_mfma_f32_16x16x32_bf16(kf0, qa[qt][0], z, 0, 0, 0);
        z = __builtin_amdgcn_mfma_f32_16x16x32_bf16(kf1, qa[qt][1], z, 0, 0, 0);
        st[kvt][qt] = z;
      }
    }
    __builtin_amdgcn_s_setprio(0);

    uint32_t W[2][2][2];   // [qt][kvt][hh]
#pragma unroll
    for (int qt = 0; qt < 2; ++qt) {
      int qrow = q0 + wh * 32 + qt * 16 + fr;
#pragma unroll
      for (int kvt = 0; kvt < 2; ++kvt) {
        float p0, p1, p2, p3;
        if (kb < qb) {
          p0 = exp2f(st[kvt][qt][0]);
          p1 = exp2f(st[kvt][qt][1]);
          p2 = exp2f(st[kvt][qt][2]);
          p3 = exp2f(st[kvt][qt][3]);
        } else {
          int kvg = kb * 64 + wk * 32 + kvt * 16 + fq * 4;
          p0 = (kvg + 0 > qrow) ? 0.f : exp2f(st[kvt][qt][0]);
          p1 = (kvg + 1 > qrow) ? 0.f : exp2f(st[kvt][qt][1]);
          p2 = (kvg + 2 > qrow) ? 0.f : exp2f(st[kvt][qt][2]);
          p3 = (kvg + 3 > qrow) ? 0.f : exp2f(st[kvt][qt][3]);
        }
        ssum[qt] += (p0 + p1) + (p2 + p3);
        W[qt][kvt][0] = cvt_pk_bf16(p0, p1);
        W[qt][kvt][1] = cvt_pk_bf16(p2, p3);
      }
    }

    union U { uint32_t u[4]; bf16x8 v; };
    U pa[2];
#pragma unroll
    for (int qt = 0; qt < 2; ++qt)
#pragma unroll
      for (int hh = 0; hh < 2; ++hh) {
        uint32_t a0 = W[qt][0][hh], b0 = W[qt][1][hh];
        asm("v_permlane32_swap_b32 %0, %1" : "+v"(a0), "+v"(b0));
        asm("v_permlane16_swap_b32 %0, %1" : "+v"(a0), "+v"(b0));
        pa[qt].u[hh] = a0; pa[qt].u[2 + hh] = b0;
      }

    __builtin_amdgcn_s_setprio(1);
#pragma unroll
    for (int ht = 0; ht < 4; ++ht) {
      int vrow = ht * 16 + fr;
      bf16x8 vb = ldfrag(Vc + vrow * 64 + ((wk * 32 + fq * 8) ^ ((vrow & 7) << 3)));
#pragma unroll
      for (int qt = 0; qt < 2; ++qt)
        accO[qt][ht] = __builtin_amdgcn_mfma_f32_16x16x32_bf16(pa[qt].v, vb, accO[qt][ht], 0, 0, 0);
    }
    __builtin_amdgcn_s_setprio(0);
    cur ^= 1;
  }

#pragma unroll
  for (int qt = 0; qt < 2; ++qt) {
    ssum[qt] += __shfl_xor(ssum[qt], 16);
    ssum[qt] += __shfl_xor(ssum[qt], 32);
  }

  __syncthreads();
  float* Ored = (float*)Ks;
  float* Sred = (float*)Vs;
  if (wk == 1) {
#pragma unroll
    for (int qt = 0; qt < 2; ++qt)
#pragma unroll
      for (int ht = 0; ht < 4; ++ht)
        *reinterpret_cast<f32x4*>(&Ored[(((wh * 2 + qt) * 4 + ht) << 8) + lane * 4]) = accO[qt][ht];
    if (fq == 0) {
      Sred[wh * 64 + fr]      = ssum[0];
      Sred[wh * 64 + 16 + fr] = ssum[1];
    }
  }
  __syncthreads();
  if (wk == 0) {
#pragma unroll
    for (int qt = 0; qt < 2; ++qt)
#pragma unroll
      for (int ht = 0; ht < 4; ++ht) {
        f32x4 o = *reinterpret_cast<const f32x4*>(&Ored[(((wh * 2 + qt) * 4 + ht) << 8) + lane * 4]);
        accO[qt][ht] += o;
      }
    float invq[2][4];
#pragma unroll
    for (int qt = 0; qt < 2; ++qt) {
      float s = ssum[qt] + Sred[wh * 64 + qt * 16 + fr];
      float inv = 1.0f / s;
#pragma unroll
      for (int r = 0; r < 4; ++r) invq[qt][r] = __shfl(inv, fq * 4 + r);
    }
#pragma unroll
    for (int qt = 0; qt < 2; ++qt)
#pragma unroll
      for (int ht = 0; ht < 4; ++ht)
#pragma unroll
        for (int r = 0; r < 4; ++r) {
          float o = accO[qt][ht][r] * invq[qt][r];
          int qr = q0 + wh * 32 + qt * 16 + fq * 4 + r;
          Ow[((size_t)b * 2048 + qr) * 1024 + h * 64 + ht * 16 + fr] = f2bf(o);
        }
  }
}

// ---------------------------------------------------------------------------
// Output projection: O[4096][1024] x Wo[1024][1024]^T + b -> y fp32
// ---------------------------------------------------------------------------
__global__ __launch_bounds__(256) void proj_gemm_kernel(
    const u16* __restrict__ Ob, const u16* __restrict__ Wob,
    const float* __restrict__ bias, float* __restrict__ out) {
  __shared__ u16 As[128 * 32];
  __shared__ u16 Bs[128 * 32];
  const int NB = 8;
  int m0 = (blockIdx.x / NB) * 128, n0 = (blockIdx.x % NB) * 128;
  f32x4 acc[4][4] = {};
  gemm128_core(Ob, Wob, m0, n0, 1024, As, Bs, acc);

  const int lane = threadIdx.x & 63, wid = threadIdx.x >> 6;
  const int wr = wid >> 1, wc = wid & 1, fq = lane >> 4, fr = lane & 15;
#pragma unroll
  for (int i = 0; i < 4; ++i)
#pragma unroll
    for (int j = 0; j < 4; ++j)
#pragma unroll
      for (int r = 0; r < 4; ++r) {
        int m = m0 + wr * 64 + i * 16 + fq * 4 + r;
        int n = n0 + wc * 64 + j * 16 + fr;
        out[(size_t)m * 1024 + n] = acc[i][j][r] + bias[n];
      }
}

// ---------------------------------------------------------------------------
extern "C" void kernel_launch(void* const* d_in, const int* in_sizes, int n_in,
                              void* d_out, int out_size, void* d_ws, size_t ws_size,
                              hipStream_t stream) {
  const float* x    = (const float*)d_in[0];
  const float* wqkv = (const float*)d_in[1];
  const float* wo   = (const float*)d_in[2];
  const float* wo_b = (const float*)d_in[3];
  float* out = (float*)d_out;

  u16* xb    = (u16*)d_ws;            // 4096*1024
  u16* wqkvb = xb    + 4194304;       // 3072*1024
  u16* wob   = wqkvb + 3145728;       // 1024*1024
  u16* q_ws  = wob   + 1048576;       // [2,16,2048,64] (pre-scaled)
  u16* k_ws  = q_ws  + 4194304;       // [2,16,2048,64]
  u16* vt_ws = k_ws  + 4194304;       // [2,16,64,2048]  (V^T)
  u16* o_ws  = vt_ws + 4194304;       // [4096,1024]

  static bool attr_set = false;
  if (!attr_set) {
    hipFuncSetAttribute((const void*)qkv_gemm_kernel,
                        hipFuncAttributeMaxDynamicSharedMemorySize, 131072);
    attr_set = true;
  }

  cvt_all<<<2048, 256, 0, stream>>>(x, wqkv, wo, xb, wqkvb, wob);
  qkv_gemm_kernel<<<512, 512, 81920, stream>>>(xb, wqkvb, q_ws, k_ws, vt_ws, out);
  attn_kernel<<<32 * 32, 256, 0, stream>>>(q_ws, k_ws, vt_ws, o_ws);
  proj_gemm_kernel<<<32 * 8, 256, 0, stream>>>(o_ws, wob, wo_b, out);
}

// Round 19
// 104.816 us; speedup vs baseline: 1.1797x; 1.0741x over previous
//
#include <hip/hip_runtime.h>
#include <cstdint>
#include <cstddef>

// ---------------------------------------------------------------------------
// MHA forward: x[2,2048,1024] fp32, wqkv[3072,1024], wo[1024,1024], wo_b[1024]
// out = concat(y[2,2048,1024], k[2,16,2048,64], v[2,16,2048,64]) fp32
// Pipeline: cvt->bf16 (fused); QKV GEMM (128x192, 2 blocks/CU, 2-phase fine
// interleave, counted vmcnt(3), Q pre-scaled); flash causal attn (r13);
// proj GEMM (NEW: 128x128 2-phase fine interleave, counted vmcnt(2)).
// ---------------------------------------------------------------------------

using bf16x8 = __attribute__((ext_vector_type(8))) __bf16;
using f32x4  = __attribute__((ext_vector_type(4))) float;
using u16    = unsigned short;

#define SOFT_SCALE 0.1803368801111244f   // 0.125 * log2(e)  (attn in exp2 domain)

// fp32 -> bf16 bits, round-to-nearest-even
__device__ __forceinline__ u16 f2bf(float f) {
  union { float f; uint32_t u; } a; a.f = f;
  uint32_t r = a.u + 0x7fffu + ((a.u >> 16) & 1u);
  return (u16)(r >> 16);
}

__device__ __forceinline__ bf16x8 ldfrag(const u16* p) {
  return *reinterpret_cast<const bf16x8*>(p);
}

__device__ __forceinline__ void gload_lds16(const void* g, void* l) {
  __builtin_amdgcn_global_load_lds((const __attribute__((address_space(1))) void*)g,
                                   (__attribute__((address_space(3))) void*)l,
                                   16, 0, 0);
}

// pack two fp32 -> one u32 of two bf16 (lo = a, hi = b), RNE
__device__ __forceinline__ uint32_t cvt_pk_bf16(float a, float b) {
  uint32_t r;
  asm("v_cvt_pk_bf16_f32 %0, %1, %2" : "=v"(r) : "v"(a), "v"(b));
  return r;
}

// ---------------------------------------------------------------------------
// fused fp32 -> bf16 convert for x, wqkv, wo (single launch)
// ---------------------------------------------------------------------------
__global__ void cvt_all(const float* __restrict__ x, const float* __restrict__ wqkv,
                        const float* __restrict__ wo,
                        u16* __restrict__ xb, u16* __restrict__ wqkvb, u16* __restrict__ wob) {
  int i = blockIdx.x * blockDim.x + threadIdx.x;
  int stride = gridDim.x * blockDim.x;
  for (; i < 2097152; i += stride) {
    const float* src; u16* dst; int j;
    if (i < 1048576)      { src = x;    dst = xb;    j = i; }
    else if (i < 1835008) { src = wqkv; dst = wqkvb; j = i - 1048576; }
    else                  { src = wo;   dst = wob;   j = i - 1835008; }
    float4 v = reinterpret_cast<const float4*>(src)[j];
    ushort4 o;
    o.x = f2bf(v.x); o.y = f2bf(v.y); o.z = f2bf(v.z); o.w = f2bf(v.w);
    reinterpret_cast<ushort4*>(dst)[j] = o;
  }
}

// ---------------------------------------------------------------------------
// QKV GEMM (r15, validated): 128x192 tiles, grid 512 = 2/CU, 80KB LDS,
// 2-phase fine interleave, counted vmcnt(3), Q pre-scaled.
// ---------------------------------------------------------------------------
__global__ __launch_bounds__(512, 2) void qkv_gemm_kernel(
    const u16* __restrict__ Xb, const u16* __restrict__ Wb,
    u16* __restrict__ Qws, u16* __restrict__ Kws, u16* __restrict__ Vtws,
    float* __restrict__ out) {
  extern __shared__ char smem[];

  const int tid = threadIdx.x, lane = tid & 63, wid = tid >> 6;
  const int wr = wid >> 2, wc = wid & 3;
  const int fq = lane >> 4, fr = lane & 15;

  // bijective chunked XCD swizzle (512 % 8 == 0)
  const int wg = (blockIdx.x & 7) * 64 + (blockIdx.x >> 3);
  const int bm = wg >> 4, bn = wg & 15;
  const int m0 = bm * 128, n0 = bn * 192;

  const char* Ab = (const char*)Xb + (size_t)m0 * 2048;
  const char* Bb = (const char*)Wb + (size_t)n0 * 2048;

  f32x4 acc[4][3] = {};

  auto stage_A = [&](int t, int h) {
    char* dst = smem + (t & 1) * 16384 + h * 8192;
    int lin = tid * 16;
    int rl  = lin >> 7;
    int col = (lin & 127) ^ ((rl & 7) << 4);
    gload_lds16(Ab + (size_t)(h * 64 + rl) * 2048 + t * 128 + col, dst + lin);
  };
  auto stage_B = [&](int t) {
    char* dst = smem + 32768 + (t & 1) * 24576;
#pragma unroll
    for (int l = 0; l < 3; ++l) {
      int lin = (l * 512 + tid) * 16;
      int rl  = lin >> 7;
      int col = (lin & 127) ^ ((rl & 7) << 4);
      gload_lds16(Bb + (size_t)rl * 2048 + t * 128 + col, dst + lin);
    }
  };

  stage_A(0, 0); stage_A(0, 1);
  stage_B(0);
  stage_B(1);
  asm volatile("s_waitcnt vmcnt(3)" ::: "memory");
  __builtin_amdgcn_s_barrier();

  bf16x8 afr[2][2];
  bf16x8 bfr[3][2];

  for (int t = 0; t < 16; ++t) {
    const char* As = smem + (t & 1) * 16384;
    const char* Bs = smem + 32768 + (t & 1) * 24576;

#pragma unroll
    for (int m = 0; m < 2; ++m) {
      int row = wr * 64 + m * 16 + fr;
#pragma unroll
      for (int ks = 0; ks < 2; ++ks)
        afr[m][ks] = *(const bf16x8*)(As + row * 128 + ((ks * 64 + fq * 16) ^ ((row & 7) << 4)));
    }
#pragma unroll
    for (int n = 0; n < 3; ++n) {
      int row = wc * 48 + n * 16 + fr;
#pragma unroll
      for (int ks = 0; ks < 2; ++ks)
        bfr[n][ks] = *(const bf16x8*)(Bs + row * 128 + ((ks * 64 + fq * 16) ^ ((row & 7) << 4)));
    }
    if (t + 1 < 16) stage_A(t + 1, 0);
    __builtin_amdgcn_s_barrier();
    asm volatile("s_waitcnt lgkmcnt(0)" ::: "memory");
    __builtin_amdgcn_sched_barrier(0);
    __builtin_amdgcn_s_setprio(1);
#pragma unroll
    for (int m = 0; m < 2; ++m)
#pragma unroll
      for (int n = 0; n < 3; ++n)
#pragma unroll
        for (int ks = 0; ks < 2; ++ks)
          acc[m][n] = __builtin_amdgcn_mfma_f32_16x16x32_bf16(afr[m][ks], bfr[n][ks], acc[m][n], 0, 0, 0);
    __builtin_amdgcn_s_setprio(0);
    __builtin_amdgcn_s_barrier();

#pragma unroll
    for (int m = 0; m < 2; ++m) {
      int row = wr * 64 + (m + 2) * 16 + fr;
#pragma unroll
      for (int ks = 0; ks < 2; ++ks)
        afr[m][ks] = *(const bf16x8*)(As + row * 128 + ((ks * 64 + fq * 16) ^ ((row & 7) << 4)));
    }
    if (t + 1 < 16) stage_A(t + 1, 1);
    if (t + 2 < 16) stage_B(t + 2);
    __builtin_amdgcn_s_barrier();
    asm volatile("s_waitcnt lgkmcnt(0)" ::: "memory");
    __builtin_amdgcn_sched_barrier(0);
    __builtin_amdgcn_s_setprio(1);
#pragma unroll
    for (int m = 0; m < 2; ++m)
#pragma unroll
      for (int n = 0; n < 3; ++n)
#pragma unroll
        for (int ks = 0; ks < 2; ++ks)
          acc[m + 2][n] = __builtin_amdgcn_mfma_f32_16x16x32_bf16(afr[m][ks], bfr[n][ks], acc[m + 2][n], 0, 0, 0);
    __builtin_amdgcn_s_setprio(0);
    if (t < 14)       asm volatile("s_waitcnt vmcnt(3)" ::: "memory");
    else if (t == 14) asm volatile("s_waitcnt vmcnt(0)" ::: "memory");
    __builtin_amdgcn_s_barrier();
  }

  const int mbase = m0 + wr * 64;
#pragma unroll
  for (int m = 0; m < 4; ++m)
#pragma unroll
    for (int n = 0; n < 3; ++n) {
      int mB = mbase + m * 16 + fq * 4;
      int ncol = n0 + wc * 48 + n * 16 + fr;
      int sect = ncol >> 10;
      int nn = ncol & 1023;
      int b = mB >> 11, s0 = mB & 2047;
      int h = nn >> 6, hd = nn & 63;
      size_t base = (((size_t)b * 16 + h) * 2048 + s0) * 64 + hd;
      float v0 = acc[m][n][0], v1 = acc[m][n][1], v2 = acc[m][n][2], v3 = acc[m][n][3];
      if (sect == 0) {
        Qws[base]       = f2bf(v0 * SOFT_SCALE);
        Qws[base + 64]  = f2bf(v1 * SOFT_SCALE);
        Qws[base + 128] = f2bf(v2 * SOFT_SCALE);
        Qws[base + 192] = f2bf(v3 * SOFT_SCALE);
      } else if (sect == 1) {
        Kws[base] = f2bf(v0); Kws[base + 64] = f2bf(v1);
        Kws[base + 128] = f2bf(v2); Kws[base + 192] = f2bf(v3);
        out[4194304 + base] = v0; out[4194304 + base + 64] = v1;
        out[4194304 + base + 128] = v2; out[4194304 + base + 192] = v3;
      } else {
        out[8388608 + base] = v0; out[8388608 + base + 64] = v1;
        out[8388608 + base + 128] = v2; out[8388608 + base + 192] = v3;
        size_t tt = ((size_t)(b * 16 + h) * 64 + hd) * 2048 + s0;
        ushort4 pk; pk.x = f2bf(v0); pk.y = f2bf(v1); pk.z = f2bf(v2); pk.w = f2bf(v3);
        *reinterpret_cast<ushort4*>(Vtws + tt) = pk;
      }
    }
}

// ---------------------------------------------------------------------------
// Flash causal attention (r13, plateau 44.5us). grid = 1024; block = 256.
// ---------------------------------------------------------------------------
__global__ __launch_bounds__(256, 4) void attn_kernel(
    const u16* __restrict__ Qw, const u16* __restrict__ Kw,
    const u16* __restrict__ Vtw, u16* __restrict__ Ow) {
  __shared__ u16 Ks[2][64 * 64];
  __shared__ u16 Vs[2][64 * 64];

  const int tid = threadIdx.x, lane = tid & 63, wid = tid >> 6;
  const int wk = wid >> 1, wh = wid & 1;
  const int fq = lane >> 4, fr = lane & 15;
  const int bh = blockIdx.x & 31;
  const int qb = 31 - (blockIdx.x >> 5);
  const int b = bh >> 4, h = bh & 15;
  const int q0 = qb * 64;

  const u16* Qbase  = Qw  + (size_t)bh * 2048 * 64;
  const u16* Kbase  = Kw  + (size_t)bh * 2048 * 64;
  const char* VtBase = (const char*)(Vtw + (size_t)bh * 64 * 2048);

#pragma unroll
  for (int f = 0; f < 2; ++f) {
    int lin = (f * 256 + tid) * 16;
    int row = lin >> 7;
    int logical = lin ^ ((row & 7) << 4);
    gload_lds16((const char*)Kbase + logical, (char*)Ks[0] + lin);
    gload_lds16(VtBase + (size_t)row * 4096 + (logical & 127), (char*)Vs[0] + lin);
  }

  bf16x8 qa[2][2];
#pragma unroll
  for (int qt = 0; qt < 2; ++qt)
#pragma unroll
    for (int kh = 0; kh < 2; ++kh)
      qa[qt][kh] = ldfrag(Qbase + (size_t)(q0 + wh * 32 + qt * 16 + fr) * 64 + kh * 32 + fq * 8);

  float ssum[2] = {0.f, 0.f};
  f32x4 accO[2][4] = {};

  int cur = 0;
  for (int kb = 0; kb <= qb; ++kb) {
    __syncthreads();

    if (kb < qb) {
      const char* kg = (const char*)(Kbase + (size_t)(kb + 1) * 64 * 64);
#pragma unroll
      for (int f = 0; f < 2; ++f) {
        int lin = (f * 256 + tid) * 16;
        int row = lin >> 7;
        int logical = lin ^ ((row & 7) << 4);
        gload_lds16(kg + logical, (char*)Ks[cur ^ 1] + lin);
        gload_lds16(VtBase + (size_t)row * 4096 + (size_t)(kb + 1) * 128 + (logical & 127),
                    (char*)Vs[cur ^ 1] + lin);
      }
    }

    const u16* Kc = Ks[cur];
    const u16* Vc = Vs[cur];

    f32x4 st[2][2];
    __builtin_amdgcn_s_setprio(1);
#pragma unroll
    for (int kvt = 0; kvt < 2; ++kvt) {
      int krow = wk * 32 + kvt * 16 + fr;
      bf16x8 kf0 = ldfrag(Kc + krow * 64 + ((fq * 8)      ^ ((krow & 7) << 3)));
      bf16x8 kf1 = ldfrag(Kc + krow * 64 + ((fq * 8 + 32) ^ ((krow & 7) << 3)));
#pragma unroll
      for (int qt = 0; qt < 2; ++qt) {
        f32x4 z = {};
        z = __builtin_amdgcn_mfma_f32_16x16x32_bf16(kf0, qa[qt][0], z, 0, 0, 0);
        z = __builtin_amdgcn_mfma_f32_16x16x32_bf16(kf1, qa[qt][1], z, 0, 0, 0);
        st[kvt][qt] = z;
      }
    }
    __builtin_amdgcn_s_setprio(0);

    uint32_t W[2][2][2];
#pragma unroll
    for (int qt = 0; qt < 2; ++qt) {
      int qrow = q0 + wh * 32 + qt * 16 + fr;
#pragma unroll
      for (int kvt = 0; kvt < 2; ++kvt) {
        float p0, p1, p2, p3;
        if (kb < qb) {
          p0 = exp2f(st[kvt][qt][0]);
          p1 = exp2f(st[kvt][qt][1]);
          p2 = exp2f(st[kvt][qt][2]);
          p3 = exp2f(st[kvt][qt][3]);
        } else {
          int kvg = kb * 64 + wk * 32 + kvt * 16 + fq * 4;
          p0 = (kvg + 0 > qrow) ? 0.f : exp2f(st[kvt][qt][0]);
          p1 = (kvg + 1 > qrow) ? 0.f : exp2f(st[kvt][qt][1]);
          p2 = (kvg + 2 > qrow) ? 0.f : exp2f(st[kvt][qt][2]);
          p3 = (kvg + 3 > qrow) ? 0.f : exp2f(st[kvt][qt][3]);
        }
        ssum[qt] += (p0 + p1) + (p2 + p3);
        W[qt][kvt][0] = cvt_pk_bf16(p0, p1);
        W[qt][kvt][1] = cvt_pk_bf16(p2, p3);
      }
    }

    union U { uint32_t u[4]; bf16x8 v; };
    U pa[2];
#pragma unroll
    for (int qt = 0; qt < 2; ++qt)
#pragma unroll
      for (int hh = 0; hh < 2; ++hh) {
        uint32_t a0 = W[qt][0][hh], b0 = W[qt][1][hh];
        asm("v_permlane32_swap_b32 %0, %1" : "+v"(a0), "+v"(b0));
        asm("v_permlane16_swap_b32 %0, %1" : "+v"(a0), "+v"(b0));
        pa[qt].u[hh] = a0; pa[qt].u[2 + hh] = b0;
      }

    __builtin_amdgcn_s_setprio(1);
#pragma unroll
    for (int ht = 0; ht < 4; ++ht) {
      int vrow = ht * 16 + fr;
      bf16x8 vb = ldfrag(Vc + vrow * 64 + ((wk * 32 + fq * 8) ^ ((vrow & 7) << 3)));
#pragma unroll
      for (int qt = 0; qt < 2; ++qt)
        accO[qt][ht] = __builtin_amdgcn_mfma_f32_16x16x32_bf16(pa[qt].v, vb, accO[qt][ht], 0, 0, 0);
    }
    __builtin_amdgcn_s_setprio(0);
    cur ^= 1;
  }

#pragma unroll
  for (int qt = 0; qt < 2; ++qt) {
    ssum[qt] += __shfl_xor(ssum[qt], 16);
    ssum[qt] += __shfl_xor(ssum[qt], 32);
  }

  __syncthreads();
  float* Ored = (float*)Ks;
  float* Sred = (float*)Vs;
  if (wk == 1) {
#pragma unroll
    for (int qt = 0; qt < 2; ++qt)
#pragma unroll
      for (int ht = 0; ht < 4; ++ht)
        *reinterpret_cast<f32x4*>(&Ored[(((wh * 2 + qt) * 4 + ht) << 8) + lane * 4]) = accO[qt][ht];
    if (fq == 0) {
      Sred[wh * 64 + fr]      = ssum[0];
      Sred[wh * 64 + 16 + fr] = ssum[1];
    }
  }
  __syncthreads();
  if (wk == 0) {
#pragma unroll
    for (int qt = 0; qt < 2; ++qt)
#pragma unroll
      for (int ht = 0; ht < 4; ++ht) {
        f32x4 o = *reinterpret_cast<const f32x4*>(&Ored[(((wh * 2 + qt) * 4 + ht) << 8) + lane * 4]);
        accO[qt][ht] += o;
      }
    float invq[2][4];
#pragma unroll
    for (int qt = 0; qt < 2; ++qt) {
      float s = ssum[qt] + Sred[wh * 64 + qt * 16 + fr];
      float inv = 1.0f / s;
#pragma unroll
      for (int r = 0; r < 4; ++r) invq[qt][r] = __shfl(inv, fq * 4 + r);
    }
#pragma unroll
    for (int qt = 0; qt < 2; ++qt)
#pragma unroll
      for (int ht = 0; ht < 4; ++ht)
#pragma unroll
        for (int r = 0; r < 4; ++r) {
          float o = accO[qt][ht][r] * invq[qt][r];
          int qr = q0 + wh * 32 + qt * 16 + fq * 4 + r;
          Ow[((size_t)b * 2048 + qr) * 1024 + h * 64 + ht * 16 + fr] = f2bf(o);
        }
  }
}

// ---------------------------------------------------------------------------
// Output projection (NEW 2-phase pipeline): O[4096][1024] x Wo[1024][1024]^T
// + bias -> y fp32. Tile 128x128, grid 32x8=256 (2 blocks/CU at 64KB LDS).
// 512 thr = 8 waves (2M x 4N), per-wave 64x32 (4m x 2n frags). BK=64.
// Stage slots: P0 A-h0(t+1); P1 A-h1(t+1) + B(t+2) both halves; boundary
// vmcnt(2) (B(t+2)'s 2 loads in flight).
// ---------------------------------------------------------------------------
__global__ __launch_bounds__(512, 2) void proj_gemm_kernel(
    const u16* __restrict__ Ob, const u16* __restrict__ Wob,
    const float* __restrict__ bias, float* __restrict__ out) {
  extern __shared__ char smem[];   // A 2x16KB @0; B 2x16KB @32768

  const int tid = threadIdx.x, lane = tid & 63, wid = tid >> 6;
  const int wr = wid >> 2, wc = wid & 3;
  const int fq = lane >> 4, fr = lane & 15;

  // bijective chunked XCD swizzle (256 % 8 == 0)
  const int wg = (blockIdx.x & 7) * 32 + (blockIdx.x >> 3);
  const int bm = wg >> 3, bn = wg & 7;
  const int m0 = bm * 128, n0 = bn * 128;

  const char* Ab = (const char*)Ob  + (size_t)m0 * 2048;
  const char* Bb = (const char*)Wob + (size_t)n0 * 2048;

  f32x4 acc[4][2] = {};

  // stage one half-tile (64 rows x 64 cols = 8KB): 1 gload_lds per thread
  auto stage = [&](int t, int mat, int h) {
    char* dst = smem + mat * 32768 + (t & 1) * 16384 + h * 8192;
    const char* src = mat ? Bb : Ab;
    int lin = tid * 16;
    int rl  = lin >> 7;
    int col = (lin & 127) ^ ((rl & 7) << 4);
    gload_lds16(src + (size_t)(h * 64 + rl) * 2048 + t * 128 + col, dst + lin);
  };

  // prologue: A(0) [2], B(0) [2], B(1) [2] -> wait until only B(1)'s 2 left
  stage(0, 0, 0); stage(0, 0, 1);
  stage(0, 1, 0); stage(0, 1, 1);
  stage(1, 1, 0); stage(1, 1, 1);
  asm volatile("s_waitcnt vmcnt(2)" ::: "memory");
  __builtin_amdgcn_s_barrier();

  bf16x8 afr[2][2];   // current m-pair (2 m x 2 ks)
  bf16x8 bfr[2][2];   // 2 n x 2 ks

  for (int t = 0; t < 16; ++t) {
    const char* As = smem + (t & 1) * 16384;
    const char* Bs = smem + 32768 + (t & 1) * 16384;

    // ---------- P0: read A m0-1 + B all; stage A-h0(t+1); MFMA m0-1 x n0-1
#pragma unroll
    for (int m = 0; m < 2; ++m) {
      int row = wr * 64 + m * 16 + fr;
#pragma unroll
      for (int ks = 0; ks < 2; ++ks)
        afr[m][ks] = *(const bf16x8*)(As + row * 128 + ((ks * 64 + fq * 16) ^ ((row & 7) << 4)));
    }
#pragma unroll
    for (int n = 0; n < 2; ++n) {
      int row = wc * 32 + n * 16 + fr;
#pragma unroll
      for (int ks = 0; ks < 2; ++ks)
        bfr[n][ks] = *(const bf16x8*)(Bs + row * 128 + ((ks * 64 + fq * 16) ^ ((row & 7) << 4)));
    }
    if (t + 1 < 16) stage(t + 1, 0, 0);
    __builtin_amdgcn_s_barrier();
    asm volatile("s_waitcnt lgkmcnt(0)" ::: "memory");
    __builtin_amdgcn_sched_barrier(0);
    __builtin_amdgcn_s_setprio(1);
#pragma unroll
    for (int m = 0; m < 2; ++m)
#pragma unroll
      for (int n = 0; n < 2; ++n)
#pragma unroll
        for (int ks = 0; ks < 2; ++ks)
          acc[m][n] = __builtin_amdgcn_mfma_f32_16x16x32_bf16(afr[m][ks], bfr[n][ks], acc[m][n], 0, 0, 0);
    __builtin_amdgcn_s_setprio(0);
    __builtin_amdgcn_s_barrier();

    // ---------- P1: read A m2-3; stage A-h1(t+1) + B(t+2) x2; MFMA m2-3 x n0-1
#pragma unroll
    for (int m = 0; m < 2; ++m) {
      int row = wr * 64 + (m + 2) * 16 + fr;
#pragma unroll
      for (int ks = 0; ks < 2; ++ks)
        afr[m][ks] = *(const bf16x8*)(As + row * 128 + ((ks * 64 + fq * 16) ^ ((row & 7) << 4)));
    }
    if (t + 1 < 16) stage(t + 1, 0, 1);
    if (t + 2 < 16) { stage(t + 2, 1, 0); stage(t + 2, 1, 1); }
    __builtin_amdgcn_s_barrier();
    asm volatile("s_waitcnt lgkmcnt(0)" ::: "memory");
    __builtin_amdgcn_sched_barrier(0);
    __builtin_amdgcn_s_setprio(1);
#pragma unroll
    for (int m = 0; m < 2; ++m)
#pragma unroll
      for (int n = 0; n < 2; ++n)
#pragma unroll
        for (int ks = 0; ks < 2; ++ks)
          acc[m + 2][n] = __builtin_amdgcn_mfma_f32_16x16x32_bf16(afr[m][ks], bfr[n][ks], acc[m + 2][n], 0, 0, 0);
    __builtin_amdgcn_s_setprio(0);
    // tile boundary: A(t+1)+B(t+1) must land; allow B(t+2)'s 2 in flight
    if (t < 14)       asm volatile("s_waitcnt vmcnt(2)" ::: "memory");
    else if (t == 14) asm volatile("s_waitcnt vmcnt(0)" ::: "memory");
    __builtin_amdgcn_s_barrier();
  }

  // ---- epilogue: + bias, fp32 writes (64B-aligned 64B segments)
  const int mbase = m0 + wr * 64;
#pragma unroll
  for (int m = 0; m < 4; ++m)
#pragma unroll
    for (int n = 0; n < 2; ++n) {
      int mB = mbase + m * 16 + fq * 4;
      int ncol = n0 + wc * 32 + n * 16 + fr;
      float bv = bias[ncol];
#pragma unroll
      for (int r = 0; r < 4; ++r)
        out[(size_t)(mB + r) * 1024 + ncol] = acc[m][n][r] + bv;
    }
}

// ---------------------------------------------------------------------------
extern "C" void kernel_launch(void* const* d_in, const int* in_sizes, int n_in,
                              void* d_out, int out_size, void* d_ws, size_t ws_size,
                              hipStream_t stream) {
  const float* x    = (const float*)d_in[0];
  const float* wqkv = (const float*)d_in[1];
  const float* wo   = (const float*)d_in[2];
  const float* wo_b = (const float*)d_in[3];
  float* out = (float*)d_out;

  u16* xb    = (u16*)d_ws;            // 4096*1024
  u16* wqkvb = xb    + 4194304;       // 3072*1024
  u16* wob   = wqkvb + 3145728;       // 1024*1024
  u16* q_ws  = wob   + 1048576;       // [2,16,2048,64] (pre-scaled)
  u16* k_ws  = q_ws  + 4194304;       // [2,16,2048,64]
  u16* vt_ws = k_ws  + 4194304;       // [2,16,64,2048]  (V^T)
  u16* o_ws  = vt_ws + 4194304;       // [4096,1024]

  static bool attr_set = false;
  if (!attr_set) {
    hipFuncSetAttribute((const void*)qkv_gemm_kernel,
                        hipFuncAttributeMaxDynamicSharedMemorySize, 131072);
    hipFuncSetAttribute((const void*)proj_gemm_kernel,
                        hipFuncAttributeMaxDynamicSharedMemorySize, 65536);
    attr_set = true;
  }

  cvt_all<<<2048, 256, 0, stream>>>(x, wqkv, wo, xb, wqkvb, wob);
  qkv_gemm_kernel<<<512, 512, 81920, stream>>>(xb, wqkvb, q_ws, k_ws, vt_ws, out);
  attn_kernel<<<32 * 32, 256, 0, stream>>>(q_ws, k_ws, vt_ws, o_ws);
  proj_gemm_kernel<<<256, 512, 65536, stream>>>(o_ws, wob, wo_b, out);
}